// Round 2
// baseline (617.077 us; speedup 1.0000x reference)
//
#include <hip/hip_runtime.h>
#include <hip/hip_bf16.h>
#include <math.h>

#define DEV __device__ __forceinline__

constexpr int B = 8, N = 1024, DIN = 256, H = 4, DATT = 64, DV = 64;
constexpr int BN = B * N;             // 8192
constexpr int HD = H * DATT;          // 256
constexpr int HDV = H * DV;           // 256
constexpr int COLS = HD + HDV;        // 512
constexpr int BHN = B * H * N;        // 32768
constexpr float EPSF = 1e-7f;

// ---------------- K1: logmap0 row scale: s = artanh(nc)/nc ----------------
__global__ void k_scale(const float* __restrict__ x, float* __restrict__ s) {
    int p = blockIdx.x * 4 + (threadIdx.x >> 6);
    int l = threadIdx.x & 63;
    const float4* xr = reinterpret_cast<const float4*>(x + (size_t)p * DIN);
    float4 u = xr[l];
    float ss = u.x * u.x + u.y * u.y + u.z * u.z + u.w * u.w;
    for (int m = 32; m; m >>= 1) ss += __shfl_xor(ss, m);
    if (l == 0) {
        float n = sqrtf(ss);
        n = fminf(fmaxf(n, EPSF), 1.0f - 1e-5f);
        float at = 0.5f * __logf((1.f + n) / (1.f - n));
        s[p] = at / n;
    }
}

// ---------------- K0: build Wcat [256][512] f32 (Wq | Wv) ----------------
__global__ void k_wcat(const float* __restrict__ Wq, const float* __restrict__ Wv,
                       float* __restrict__ Wc) {
    int idx = blockIdx.x * 256 + threadIdx.x;   // < 256*512
    int k = idx >> 9, c = idx & 511;
    int cc = c & 255;
    int h = cc >> 6, e = cc & 63;
    const float* src = (c < HD) ? Wq : Wv;
    Wc[idx] = src[(h * DIN + k) * 64 + e];
}

// ---------------- K2: GEMM h_all[8192][512] = (s*x)[8192][256] @ Wc ----------------
__global__ __launch_bounds__(256) void k_gemm(const float* __restrict__ x,
                                              const float* __restrict__ s,
                                              const float* __restrict__ Wc,
                                              float* __restrict__ hall) {
    __shared__ float As[16][68];
    __shared__ float Bs[16][68];
    int bm = blockIdx.x, bn = blockIdx.y;
    int tid = threadIdx.x;
    int ty = tid >> 4, tx = tid & 15;
    float acc[4][4] = {};
    int rowbase = bm * 64, colbase = bn * 64;
    int am = tid >> 2;
    int ak = (tid & 3) * 4;
    float sc = s[rowbase + am];
    for (int kt = 0; kt < DIN; kt += 16) {
        float4 u = *reinterpret_cast<const float4*>(x + (size_t)(rowbase + am) * DIN + kt + ak);
        As[ak + 0][am] = u.x * sc;
        As[ak + 1][am] = u.y * sc;
        As[ak + 2][am] = u.z * sc;
        As[ak + 3][am] = u.w * sc;
        int bk = tid >> 4, bc = (tid & 15) * 4;
        float4 w4 = *reinterpret_cast<const float4*>(Wc + (size_t)(kt + bk) * COLS + colbase + bc);
        *reinterpret_cast<float4*>(&Bs[bk][bc]) = w4;
        __syncthreads();
        for (int k = 0; k < 16; k++) {
            float4 a4 = *reinterpret_cast<const float4*>(&As[k][ty * 4]);
            float4 b4 = *reinterpret_cast<const float4*>(&Bs[k][tx * 4]);
            float av[4] = {a4.x, a4.y, a4.z, a4.w};
            float bv[4] = {b4.x, b4.y, b4.z, b4.w};
            for (int i = 0; i < 4; i++)
                for (int j = 0; j < 4; j++) acc[i][j] = fmaf(av[i], bv[j], acc[i][j]);
        }
        __syncthreads();
    }
    for (int i = 0; i < 4; i++) {
        float4 o = make_float4(acc[i][0], acc[i][1], acc[i][2], acc[i][3]);
        *reinterpret_cast<float4*>(hall + (size_t)(rowbase + ty * 4 + i) * COLS + colbase + tx * 4) = o;
    }
}

// ---------------- K2b: es/ed dot products, layout [B][H][N] ----------------
__global__ void k_esed(const float* __restrict__ hall, const float* __restrict__ aqs,
                       const float* __restrict__ aqd, const float* __restrict__ avs,
                       const float* __restrict__ avd, float* __restrict__ esq,
                       float* __restrict__ edq, float* __restrict__ esv,
                       float* __restrict__ edv) {
    int p = blockIdx.x;
    int h = threadIdx.x >> 6, e = threadIdx.x & 63;
    float hq = hall[(size_t)p * COLS + h * 64 + e];
    float hv = hall[(size_t)p * COLS + 256 + h * 64 + e];
    float v1 = hq * aqs[h * 64 + e];
    float v2 = hq * aqd[h * 64 + e];
    float v3 = hv * avs[h * 64 + e];
    float v4 = hv * avd[h * 64 + e];
    for (int m = 32; m; m >>= 1) {
        v1 += __shfl_xor(v1, m); v2 += __shfl_xor(v2, m);
        v3 += __shfl_xor(v3, m); v4 += __shfl_xor(v4, m);
    }
    if (e == 0) {
        int b = p >> 10, n = p & 1023;
        int o = (b * H + h) * N + n;
        esq[o] = v1; edq[o] = v2; esv[o] = v3; edv[o] = v4;
    }
}

// ---------------- K3a: per-row softmax stats (max,sum) for q and v ----------------
__global__ void k_stats(const float* __restrict__ adj, const float* __restrict__ esq,
                        const float* __restrict__ edq, const float* __restrict__ esv,
                        const float* __restrict__ edv, float* __restrict__ stats) {
    int bid = blockIdx.x;                 // (b*H + h)*N + i
    int i = bid & 1023;
    int bh = bid >> 10;
    int b = bh >> 2;
    int t = threadIdx.x;                  // 128 threads, 8 j each
    float esqi = esq[bid], esvi = esv[bid];
    const float* arow = adj + (size_t)(b * N + i) * N + t * 8;
    const float* edqr = edq + (size_t)bh * N + t * 8;
    const float* edvr = edv + (size_t)bh * N + t * 8;
    float4 a0 = *reinterpret_cast<const float4*>(arow);
    float4 a1 = *reinterpret_cast<const float4*>(arow + 4);
    float am[8] = {a0.x, a0.y, a0.z, a0.w, a1.x, a1.y, a1.z, a1.w};
    float4 q0 = *reinterpret_cast<const float4*>(edqr);
    float4 q1 = *reinterpret_cast<const float4*>(edqr + 4);
    float4 w0 = *reinterpret_cast<const float4*>(edvr);
    float4 w1 = *reinterpret_cast<const float4*>(edvr + 4);
    float edqv[8] = {q0.x, q0.y, q0.z, q0.w, q1.x, q1.y, q1.z, q1.w};
    float edvv[8] = {w0.x, w0.y, w0.z, w0.w, w1.x, w1.y, w1.z, w1.w};
    float eq[8], ev[8];
    float mq = -1e30f, mv = -1e30f;
    for (int j = 0; j < 8; j++) {
        bool msk = am[j] > 0.f;
        float q = esqi + edqv[j]; q = fmaxf(q, 0.2f * q);
        float v = esvi + edvv[j]; v = fmaxf(v, 0.2f * v);
        eq[j] = msk ? q : -1e30f;
        ev[j] = msk ? v : -1e30f;
        mq = fmaxf(mq, eq[j]); mv = fmaxf(mv, ev[j]);
    }
    __shared__ float red[2][2];
    __shared__ float red2[2][2];
    for (int m = 32; m; m >>= 1) { mq = fmaxf(mq, __shfl_xor(mq, m)); mv = fmaxf(mv, __shfl_xor(mv, m)); }
    int w = t >> 6;
    if ((t & 63) == 0) { red[w][0] = mq; red[w][1] = mv; }
    __syncthreads();
    mq = fmaxf(red[0][0], red[1][0]);
    mv = fmaxf(red[0][1], red[1][1]);
    float sq_ = 0.f, sv_ = 0.f;
    for (int j = 0; j < 8; j++) { sq_ += __expf(eq[j] - mq); sv_ += __expf(ev[j] - mv); }
    for (int m = 32; m; m >>= 1) { sq_ += __shfl_xor(sq_, m); sv_ += __shfl_xor(sv_, m); }
    if ((t & 63) == 0) { red2[w][0] = sq_; red2[w][1] = sv_; }
    __syncthreads();
    if (t == 0) {
        stats[bid] = mq;
        stats[BHN + bid] = red2[0][0] + red2[1][0];
        stats[2 * BHN + bid] = mv;
        stats[3 * BHN + bid] = red2[0][1] + red2[1][1];
    }
}

// ---------------- K3b: fused GAT aggregation (q and v) ----------------
__global__ __launch_bounds__(256) void k_aggr(const float* __restrict__ adj,
        const float* __restrict__ hall, const float* __restrict__ esq,
        const float* __restrict__ edq, const float* __restrict__ esv,
        const float* __restrict__ edv, const float* __restrict__ stats,
        float* __restrict__ outq, float* __restrict__ outv) {
    int it = blockIdx.x, h = blockIdx.y, b = blockIdx.z;
    int i0 = it * 32;
    int t = threadIdx.x;
    __shared__ float hcat[64][132];
    __shared__ float wq[32][65], wv[32][65];
    __shared__ float c_esq[32], c_mq[32], c_isq[32], c_esv[32], c_mv[32], c_isv[32];
    __shared__ float c_edq[64], c_edv[64];
    int bh = b * H + h;
    if (t < 32) {
        int bi = bh * N + i0 + t;
        c_esq[t] = esq[bi]; c_esv[t] = esv[bi];
        c_mq[t] = stats[bi];           c_isq[t] = 1.f / stats[BHN + bi];
        c_mv[t] = stats[2 * BHN + bi]; c_isv[t] = 1.f / stats[3 * BHN + bi];
    }
    float acc[16] = {};
    int ds = t >> 5, il = t & 31;
    for (int jt = 0; jt < 16; jt++) {
        int j0 = jt * 64;
        __syncthreads();
        {   // stage hcat[64][128] and ed tiles
            int row = t >> 2, g = (t & 3) * 8;
            const float* src = hall + (size_t)(b * N + j0 + row) * COLS;
            float4* dst = reinterpret_cast<float4*>(&hcat[row][0]);
            for (int u = 0; u < 8; u++) {
                int c4 = g + u;
                float4 vv = *reinterpret_cast<const float4*>(
                    src + (c4 < 16 ? h * 64 + c4 * 4 : 256 + h * 64 + (c4 - 16) * 4));
                dst[c4] = vv;
            }
            if (t < 64) { int bj = bh * N + j0 + t; c_edq[t] = edq[bj]; c_edv[t] = edv[bj]; }
        }
        __syncthreads();
        // weight tiles
        for (int u = 0; u < 8; u++) {
            int e = t + 256 * u;
            int wil = e >> 6, wjl = e & 63;
            float am = adj[(size_t)(b * N + i0 + wil) * N + j0 + wjl];
            float q = c_esq[wil] + c_edq[wjl]; q = fmaxf(q, 0.2f * q);
            float v = c_esv[wil] + c_edv[wjl]; v = fmaxf(v, 0.2f * v);
            wq[wil][wjl] = am > 0.f ? __expf(q - c_mq[wil]) * c_isq[wil] : 0.f;
            wv[wil][wjl] = am > 0.f ? __expf(v - c_mv[wil]) * c_isv[wil] : 0.f;
        }
        __syncthreads();
        const float* wrow = (ds < 4) ? &wq[il][0] : &wv[il][0];
        for (int jl = 0; jl < 64; jl++) {
            float w = wrow[jl];
            const float4* hp = reinterpret_cast<const float4*>(&hcat[jl][ds * 16]);
            for (int u4 = 0; u4 < 4; u4++) {
                float4 h4 = hp[u4];
                acc[u4 * 4 + 0] = fmaf(w, h4.x, acc[u4 * 4 + 0]);
                acc[u4 * 4 + 1] = fmaf(w, h4.y, acc[u4 * 4 + 1]);
                acc[u4 * 4 + 2] = fmaf(w, h4.z, acc[u4 * 4 + 2]);
                acc[u4 * 4 + 3] = fmaf(w, h4.w, acc[u4 * 4 + 3]);
            }
        }
    }
    float* dst = (ds < 4) ? (outq + (size_t)(b * N + i0 + il) * HD + h * 64 + ds * 16)
                          : (outv + (size_t)(b * N + i0 + il) * HDV + h * 64 + (ds - 4) * 16);
    for (int u4 = 0; u4 < 4; u4++)
        *reinterpret_cast<float4*>(dst + u4 * 4) =
            make_float4(acc[u4 * 4], acc[u4 * 4 + 1], acc[u4 * 4 + 2], acc[u4 * 4 + 3]);
}

// ---------------- K4: expmap0 for query (per-head) and value (concat) ----------------
__global__ void k_expmap(const float* __restrict__ outq, const float* __restrict__ outv,
                         float* __restrict__ query, float* __restrict__ sq,
                         float* __restrict__ val) {
    int p = blockIdx.x, t = threadIdx.x;
    int h = t >> 6, e = t & 63;
    float v = outq[(size_t)p * HD + t];
    float ss = v * v;
    for (int m = 32; m; m >>= 1) ss += __shfl_xor(ss, m);
    float n = fmaxf(sqrtf(ss), EPSF);
    float tn = tanhf(n);
    query[(size_t)p * HD + t] = v * (tn / n);
    if (e == 0) sq[h * BN + p] = tn * tn;

    float vv = outv[(size_t)p * HDV + t];
    float s2 = vv * vv;
    for (int m = 32; m; m >>= 1) s2 += __shfl_xor(s2, m);
    __shared__ float part[4];
    if (e == 0) part[h] = s2;
    __syncthreads();
    float tot = part[0] + part[1] + part[2] + part[3];
    float nv = fmaxf(sqrtf(tot), EPSF);
    float sclv = tanhf(nv) / nv;
    val[(size_t)p * HDV + t] = vv * sclv;
}

// ---------------- K5: scrambled pair-dist + tanh + head-mean -> m (pre-symmetrize) ----
// reshape(-1,B,N,N) closed form: h=m2%4, m=(n2%4)*256+m2/4, n=(b2*256+n2/4)%1024, b=2a+b2/4
__global__ __launch_bounds__(256) void k_att(const float* __restrict__ query,
        const float* __restrict__ sq, const float* __restrict__ rr,
        const float* __restrict__ tt, float* __restrict__ m_out) {
    int kc = blockIdx.x >> 1, mh = blockIdx.x & 1;
    int c = blockIdx.y >> 2, h = blockIdx.y & 3;
    int b2 = blockIdx.z;
    __shared__ float Xs[64][68];
    __shared__ float Ys[128][68];
    __shared__ float sqX[64], sqY[128];
    int t = threadIdx.x;
    int nstart = (b2 * 256 + kc * 64) & 1023;
    int mstart = c * 256 + mh * 128;
    int ti = t >> 4, tm = t & 15;
    float tacc[4][8] = {};
    for (int a = 0; a < 4; a++) {
        int b = 2 * a + (b2 >> 2);
        __syncthreads();
        {   // stage X: 64 rows x 64 dims
            int row = t >> 2, g = (t & 3) * 4;
            const float* src = query + (size_t)(b * N + nstart + row) * HD + h * 64;
            float4* dst = reinterpret_cast<float4*>(&Xs[row][0]);
            for (int u = 0; u < 4; u++) dst[g + u] = *reinterpret_cast<const float4*>(src + (g + u) * 4);
            if (t < 64) sqX[t] = sq[h * BN + b * N + nstart + t];
        }
        {   // stage Y: 128 rows x 64 dims
            int row = t >> 1, g = (t & 1) * 8;
            const float* src = query + (size_t)(b * N + mstart + row) * HD + h * 64;
            float4* dst = reinterpret_cast<float4*>(&Ys[row][0]);
            for (int u = 0; u < 8; u++) dst[g + u] = *reinterpret_cast<const float4*>(src + (g + u) * 4);
            if (t < 128) sqY[t] = sq[h * BN + b * N + mstart + t];
        }
        __syncthreads();
        float ra = rr[a], ta = tt[a];
        float dot[4][8] = {};
        for (int d4 = 0; d4 < 16; d4++) {
            float4 xv[4], yv[8];
            for (int ii = 0; ii < 4; ii++) xv[ii] = *reinterpret_cast<const float4*>(&Xs[ti + 16 * ii][d4 * 4]);
            for (int jj = 0; jj < 8; jj++) yv[jj] = *reinterpret_cast<const float4*>(&Ys[tm + 16 * jj][d4 * 4]);
            for (int ii = 0; ii < 4; ii++)
                for (int jj = 0; jj < 8; jj++) {
                    dot[ii][jj] = fmaf(xv[ii].x, yv[jj].x, dot[ii][jj]);
                    dot[ii][jj] = fmaf(xv[ii].y, yv[jj].y, dot[ii][jj]);
                    dot[ii][jj] = fmaf(xv[ii].z, yv[jj].z, dot[ii][jj]);
                    dot[ii][jj] = fmaf(xv[ii].w, yv[jj].w, dot[ii][jj]);
                }
        }
        for (int ii = 0; ii < 4; ii++) {
            float sx = sqX[ti + 16 * ii];
            for (int jj = 0; jj < 8; jj++) {
                float sy = sqY[tm + 16 * jj];
                float diff = fmaxf(sx + sy - 2.f * dot[ii][jj], 0.f);
                float den = fmaxf((1.f - sx) * (1.f - sy), EPSF);
                float z = fmaxf(1.f + 2.f * diff / den, 1.f + EPSF);
                float dist = __logf(z + sqrtf(z * z - 1.f));
                float uarg = (ra - dist) * ta;
                float ex = __expf(2.f * uarg);
                tacc[ii][jj] += 1.f - 2.f / (ex + 1.f);   // tanh, NaN-safe
            }
        }
    }
    for (int ii = 0; ii < 4; ii++) {
        int n2 = c + 4 * (kc * 64 + ti + 16 * ii);
        size_t base = ((size_t)b2 << 20) + ((size_t)n2 << 10);
        for (int jj = 0; jj < 8; jj++) {
            int mloc = mh * 128 + tm + 16 * jj;
            int m2 = 4 * mloc + h;
            m_out[base + m2] = 0.25f * tacc[ii][jj];
        }
    }
}

// ---------------- K6: in-place symmetrize on d_out att region ----------------
__global__ void k_sym(float* __restrict__ m) {
    int ti = blockIdx.x, tj = blockIdx.y, b = blockIdx.z;
    if (ti > tj) return;
    __shared__ float A[32][33], Bt[32][33];
    int t = threadIdx.x;
    int r = t >> 3, c4 = (t & 7) * 4;
    size_t baseA = ((size_t)b << 20) + (size_t)(ti * 32) * N + tj * 32;
    size_t baseB = ((size_t)b << 20) + (size_t)(tj * 32) * N + ti * 32;
    float4 ua = *reinterpret_cast<const float4*>(m + baseA + (size_t)r * N + c4);
    float4 ub = *reinterpret_cast<const float4*>(m + baseB + (size_t)r * N + c4);
    A[r][c4 + 0] = ua.x; A[r][c4 + 1] = ua.y; A[r][c4 + 2] = ua.z; A[r][c4 + 3] = ua.w;
    Bt[r][c4 + 0] = ub.x; Bt[r][c4 + 1] = ub.y; Bt[r][c4 + 2] = ub.z; Bt[r][c4 + 3] = ub.w;
    __syncthreads();
    for (int u = 0; u < 4; u++) {
        int cc = c4 + u;
        float oa = 0.5f * (A[r][cc] + Bt[cc][r]);
        float ob = 0.5f * (Bt[r][cc] + A[cc][r]);
        m[baseA + (size_t)r * N + cc] = oa;
        m[baseB + (size_t)r * N + cc] = ob;
    }
}

extern "C" void kernel_launch(void* const* d_in, const int* in_sizes, int n_in,
                              void* d_out, int out_size, void* d_ws, size_t ws_size,
                              hipStream_t stream) {
    const float* x   = (const float*)d_in[0];
    const float* adj = (const float*)d_in[1];
    const float* Wq  = (const float*)d_in[3];
    const float* aqs = (const float*)d_in[4];
    const float* aqd = (const float*)d_in[5];
    const float* Wv  = (const float*)d_in[6];
    const float* avs = (const float*)d_in[7];
    const float* avd = (const float*)d_in[8];
    const float* rr  = (const float*)d_in[9];
    const float* tt  = (const float*)d_in[10];

    float* ws = (float*)d_ws;
    float* s     = ws;                            // 8192
    float* Wc    = s + BN;                        // 131072
    float* hall  = Wc + 256 * COLS;               // 4194304
    float* esq   = hall + (size_t)BN * COLS;      // 32768 x4
    float* edq   = esq + BHN;
    float* esv   = edq + BHN;
    float* edv   = esv + BHN;
    float* stats = edv + BHN;                     // 4*BHN
    float* outq  = stats + 4 * BHN;               // 2097152
    float* outv  = outq + (size_t)BN * HD;        // 2097152
    float* query = outq;                          // in-place over outq (element-local)
    float* sq    = outv + (size_t)BN * HDV;       // 32768
    size_t need = (size_t)(sq + H * BN - ws) * sizeof(float);
    if (ws_size < need) return;                   // ws too small: bail visibly

    float* val  = (float*)d_out;
    float* matt = (float*)d_out + (size_t)BN * HDV;

    k_scale<<<BN / 4, 256, 0, stream>>>(x, s);
    k_wcat<<<(256 * COLS) / 256, 256, 0, stream>>>(Wq, Wv, Wc);
    k_gemm<<<dim3(BN / 64, COLS / 64), 256, 0, stream>>>(x, s, Wc, hall);
    k_esed<<<BN, 256, 0, stream>>>(hall, aqs, aqd, avs, avd, esq, edq, esv, edv);
    k_stats<<<BHN, 128, 0, stream>>>(adj, esq, edq, esv, edv, stats);
    k_aggr<<<dim3(32, H, B), 256, 0, stream>>>(adj, hall, esq, edq, esv, edv, stats, outq, outv);
    k_expmap<<<BN, 256, 0, stream>>>(outq, outv, query, sq, val);
    k_att<<<dim3(8, 16, 8), 256, 0, stream>>>(query, sq, rr, tt, matt);
    k_sym<<<dim3(32, 32, 8), 256, 0, stream>>>(matt);
}

// Round 3
// 344.768 us; speedup vs baseline: 1.7898x; 1.7898x over previous
//
#include <hip/hip_runtime.h>
#include <hip/hip_bf16.h>
#include <math.h>

#define DEV __device__ __forceinline__

constexpr int B = 8, N = 1024, DIN = 256, H = 4, DATT = 64, DV = 64;
constexpr int BN = B * N;             // 8192
constexpr int HD = H * DATT;          // 256
constexpr int HDV = H * DV;           // 256
constexpr int COLS = HD + HDV;        // 512
constexpr int BHN = B * H * N;        // 32768
constexpr float EPSF = 1e-7f;

using short8 = __attribute__((ext_vector_type(8))) short;
using f32x4  = __attribute__((ext_vector_type(4))) float;

DEV unsigned short f2bf(float f) {
    __hip_bfloat16 h = __float2bfloat16(f);
    return *reinterpret_cast<unsigned short*>(&h);
}

// ---------------- K1: logmap0 row scale: s = artanh(nc)/nc ----------------
__global__ void k_scale(const float* __restrict__ x, float* __restrict__ s) {
    int p = blockIdx.x * 4 + (threadIdx.x >> 6);
    int l = threadIdx.x & 63;
    const float4* xr = reinterpret_cast<const float4*>(x + (size_t)p * DIN);
    float4 u = xr[l];
    float ss = u.x * u.x + u.y * u.y + u.z * u.z + u.w * u.w;
    for (int m = 32; m; m >>= 1) ss += __shfl_xor(ss, m);
    if (l == 0) {
        float n = sqrtf(ss);
        n = fminf(fmaxf(n, EPSF), 1.0f - 1e-5f);
        float at = 0.5f * __logf((1.f + n) / (1.f - n));
        s[p] = at / n;
    }
}

// ---------------- K0: build Wcat [256][512] f32 (Wq | Wv) ----------------
__global__ void k_wcat(const float* __restrict__ Wq, const float* __restrict__ Wv,
                       float* __restrict__ Wc) {
    int idx = blockIdx.x * 256 + threadIdx.x;   // < 256*512
    int k = idx >> 9, c = idx & 511;
    int cc = c & 255;
    int h = cc >> 6, e = cc & 63;
    const float* src = (c < HD) ? Wq : Wv;
    Wc[idx] = src[(h * DIN + k) * 64 + e];
}

// ---------------- K2: GEMM h_all[8192][512] = (s*x)[8192][256] @ Wc ----------------
__global__ __launch_bounds__(256) void k_gemm(const float* __restrict__ x,
                                              const float* __restrict__ s,
                                              const float* __restrict__ Wc,
                                              float* __restrict__ hall) {
    __shared__ float As[16][68];
    __shared__ float Bs[16][68];
    int bm = blockIdx.x, bn = blockIdx.y;
    int tid = threadIdx.x;
    int ty = tid >> 4, tx = tid & 15;
    float acc[4][4] = {};
    int rowbase = bm * 64, colbase = bn * 64;
    int am = tid >> 2;
    int ak = (tid & 3) * 4;
    float sc = s[rowbase + am];
    for (int kt = 0; kt < DIN; kt += 16) {
        float4 u = *reinterpret_cast<const float4*>(x + (size_t)(rowbase + am) * DIN + kt + ak);
        As[ak + 0][am] = u.x * sc;
        As[ak + 1][am] = u.y * sc;
        As[ak + 2][am] = u.z * sc;
        As[ak + 3][am] = u.w * sc;
        int bk = tid >> 4, bc = (tid & 15) * 4;
        float4 w4 = *reinterpret_cast<const float4*>(Wc + (size_t)(kt + bk) * COLS + colbase + bc);
        *reinterpret_cast<float4*>(&Bs[bk][bc]) = w4;
        __syncthreads();
        for (int k = 0; k < 16; k++) {
            float4 a4 = *reinterpret_cast<const float4*>(&As[k][ty * 4]);
            float4 b4 = *reinterpret_cast<const float4*>(&Bs[k][tx * 4]);
            float av[4] = {a4.x, a4.y, a4.z, a4.w};
            float bv[4] = {b4.x, b4.y, b4.z, b4.w};
            for (int i = 0; i < 4; i++)
                for (int j = 0; j < 4; j++) acc[i][j] = fmaf(av[i], bv[j], acc[i][j]);
        }
        __syncthreads();
    }
    for (int i = 0; i < 4; i++) {
        float4 o = make_float4(acc[i][0], acc[i][1], acc[i][2], acc[i][3]);
        *reinterpret_cast<float4*>(hall + (size_t)(rowbase + ty * 4 + i) * COLS + colbase + tx * 4) = o;
    }
}

// ---------------- K2b: es/ed dot products, layout [B][H][N] ----------------
__global__ void k_esed(const float* __restrict__ hall, const float* __restrict__ aqs,
                       const float* __restrict__ aqd, const float* __restrict__ avs,
                       const float* __restrict__ avd, float* __restrict__ esq,
                       float* __restrict__ edq, float* __restrict__ esv,
                       float* __restrict__ edv) {
    int p = blockIdx.x;
    int h = threadIdx.x >> 6, e = threadIdx.x & 63;
    float hq = hall[(size_t)p * COLS + h * 64 + e];
    float hv = hall[(size_t)p * COLS + 256 + h * 64 + e];
    float v1 = hq * aqs[h * 64 + e];
    float v2 = hq * aqd[h * 64 + e];
    float v3 = hv * avs[h * 64 + e];
    float v4 = hv * avd[h * 64 + e];
    for (int m = 32; m; m >>= 1) {
        v1 += __shfl_xor(v1, m); v2 += __shfl_xor(v2, m);
        v3 += __shfl_xor(v3, m); v4 += __shfl_xor(v4, m);
    }
    if (e == 0) {
        int b = p >> 10, n = p & 1023;
        int o = (b * H + h) * N + n;
        esq[o] = v1; edq[o] = v2; esv[o] = v3; edv[o] = v4;
    }
}

// ---------------- K3a: per-row softmax stats (max,sum) for q and v ----------------
__global__ void k_stats(const float* __restrict__ adj, const float* __restrict__ esq,
                        const float* __restrict__ edq, const float* __restrict__ esv,
                        const float* __restrict__ edv, float* __restrict__ stats) {
    int bid = blockIdx.x;                 // (b*H + h)*N + i
    int i = bid & 1023;
    int bh = bid >> 10;
    int b = bh >> 2;
    int t = threadIdx.x;                  // 128 threads, 8 j each
    float esqi = esq[bid], esvi = esv[bid];
    const float* arow = adj + (size_t)(b * N + i) * N + t * 8;
    const float* edqr = edq + (size_t)bh * N + t * 8;
    const float* edvr = edv + (size_t)bh * N + t * 8;
    float4 a0 = *reinterpret_cast<const float4*>(arow);
    float4 a1 = *reinterpret_cast<const float4*>(arow + 4);
    float am[8] = {a0.x, a0.y, a0.z, a0.w, a1.x, a1.y, a1.z, a1.w};
    float4 q0 = *reinterpret_cast<const float4*>(edqr);
    float4 q1 = *reinterpret_cast<const float4*>(edqr + 4);
    float4 w0 = *reinterpret_cast<const float4*>(edvr);
    float4 w1 = *reinterpret_cast<const float4*>(edvr + 4);
    float edqv[8] = {q0.x, q0.y, q0.z, q0.w, q1.x, q1.y, q1.z, q1.w};
    float edvv[8] = {w0.x, w0.y, w0.z, w0.w, w1.x, w1.y, w1.z, w1.w};
    float eq[8], ev[8];
    float mq = -1e30f, mv = -1e30f;
    for (int j = 0; j < 8; j++) {
        bool msk = am[j] > 0.f;
        float q = esqi + edqv[j]; q = fmaxf(q, 0.2f * q);
        float v = esvi + edvv[j]; v = fmaxf(v, 0.2f * v);
        eq[j] = msk ? q : -1e30f;
        ev[j] = msk ? v : -1e30f;
        mq = fmaxf(mq, eq[j]); mv = fmaxf(mv, ev[j]);
    }
    __shared__ float red[2][2];
    __shared__ float red2[2][2];
    for (int m = 32; m; m >>= 1) { mq = fmaxf(mq, __shfl_xor(mq, m)); mv = fmaxf(mv, __shfl_xor(mv, m)); }
    int w = t >> 6;
    if ((t & 63) == 0) { red[w][0] = mq; red[w][1] = mv; }
    __syncthreads();
    mq = fmaxf(red[0][0], red[1][0]);
    mv = fmaxf(red[0][1], red[1][1]);
    float sq_ = 0.f, sv_ = 0.f;
    for (int j = 0; j < 8; j++) { sq_ += __expf(eq[j] - mq); sv_ += __expf(ev[j] - mv); }
    for (int m = 32; m; m >>= 1) { sq_ += __shfl_xor(sq_, m); sv_ += __shfl_xor(sv_, m); }
    if ((t & 63) == 0) { red2[w][0] = sq_; red2[w][1] = sv_; }
    __syncthreads();
    if (t == 0) {
        stats[bid] = mq;
        stats[BHN + bid] = red2[0][0] + red2[1][0];
        stats[2 * BHN + bid] = mv;
        stats[3 * BHN + bid] = red2[0][1] + red2[1][1];
    }
}

// ---------------- K3b: MFMA GAT aggregation (q and v fused) ----------------
// Per block: 32 i-rows x (64 q-dims | 64 v-dims) for one (b,h).
// Waves 0,1 -> q (row halves), waves 2,3 -> v. A-frag (softmax weights)
// computed per-lane in registers (each lane computes exactly the 8 weights
// its MFMA fragment needs). B-frag = h vectors staged transposed in LDS bf16.
__global__ __launch_bounds__(256) void k_aggr(const float* __restrict__ adj,
        const float* __restrict__ hall, const float* __restrict__ esq,
        const float* __restrict__ edq, const float* __restrict__ esv,
        const float* __restrict__ edv, const float* __restrict__ stats,
        float* __restrict__ outq, float* __restrict__ outv) {
    int it = blockIdx.x, h = blockIdx.y, b = blockIdx.z;
    int i0 = it * 32;
    int t = threadIdx.x;
    int lane = t & 63, wv = t >> 6;
    int mh = wv & 1, kind = wv >> 1;          // 0=q, 1=v
    int bh = b * H + h;

    __shared__ __align__(16) unsigned short hT[128][40];  // [e][j] bf16; 80B rows (b128-aligned)

    // per-lane row constants (i fixed for this lane's whole K-loop)
    int i = i0 + mh * 16 + (lane & 15);
    int bi = bh * N + i;
    const float* es_p = kind ? esv : esq;
    const float* ed_p = kind ? edv : edq;
    float es_i = es_p[bi];
    float m_i  = stats[2 * kind * BHN + bi];
    float is_i = 1.f / stats[(2 * kind + 1) * BHN + bi];
    const float* adjrow = adj + (size_t)(b * N + i) * N;
    const float* edrow  = ed_p + (size_t)bh * N;
    int klo = lane >> 4;                      // k-group 0..3 (k = klo*8+u)

    // staging assignment: thread -> j-pair (2 cols) x 8 e-rows
    int jp = t & 15;                          // j = 2*jp, 2*jp+1
    int eg = t >> 4;                          // 0..15 ; e = eg*8 + u
    int ebase = eg * 8;
    int col0 = (ebase < 64) ? (h * 64 + ebase) : (256 + h * 64 + (ebase - 64));

    f32x4 acc[4] = {};
    int erow = kind * 64 + (lane & 15);       // B-frag LDS row base (+ nt*16)

    for (int jt = 0; jt < 32; jt++) {
        int j0 = jt * 32;
        // A-frag source data (global only, overlaps the barrier wait)
        float4 a0 = *reinterpret_cast<const float4*>(adjrow + j0 + klo * 8);
        float4 a1 = *reinterpret_cast<const float4*>(adjrow + j0 + klo * 8 + 4);
        float4 e0 = *reinterpret_cast<const float4*>(edrow + j0 + klo * 8);
        float4 e1 = *reinterpret_cast<const float4*>(edrow + j0 + klo * 8 + 4);
        const float* r0 = hall + (size_t)(b * N + j0 + 2 * jp) * COLS + col0;
        float4 f0a = *reinterpret_cast<const float4*>(r0);
        float4 f0b = *reinterpret_cast<const float4*>(r0 + 4);
        float4 f1a = *reinterpret_cast<const float4*>(r0 + COLS);
        float4 f1b = *reinterpret_cast<const float4*>(r0 + COLS + 4);
        __syncthreads();                      // prev iter's B-reads complete
        {   // stage hT[e][j] (transposed, 2 bf16 per b32 word, rotated issue order)
            float lof[8] = {f0a.x, f0a.y, f0a.z, f0a.w, f0b.x, f0b.y, f0b.z, f0b.w};
            float hif[8] = {f1a.x, f1a.y, f1a.z, f1a.w, f1b.x, f1b.y, f1b.z, f1b.w};
            for (int uu = 0; uu < 8; uu++) {
                int u = (uu + eg) & 7;        // rotate to spread banks across eg
                unsigned int wword = (unsigned int)f2bf(lof[u]) |
                                     ((unsigned int)f2bf(hif[u]) << 16);
                reinterpret_cast<unsigned int*>(&hT[ebase + u][0])[jp] = wword;
            }
        }
        // A-frag: this lane's 8 softmax weights -> bf16 registers
        float av[8] = {a0.x, a0.y, a0.z, a0.w, a1.x, a1.y, a1.z, a1.w};
        float ev[8] = {e0.x, e0.y, e0.z, e0.w, e1.x, e1.y, e1.z, e1.w};
        short8 afrag;
        for (int u = 0; u < 8; u++) {
            float q = es_i + ev[u];
            q = fmaxf(q, 0.2f * q);
            float wgt = (av[u] > 0.f) ? __expf(q - m_i) * is_i : 0.f;
            afrag[u] = (short)f2bf(wgt);
        }
        __syncthreads();                      // staging visible
        for (int nt = 0; nt < 4; nt++) {
            short8 bfrag = *reinterpret_cast<const short8*>(&hT[erow + nt * 16][klo * 8]);
            acc[nt] = __builtin_amdgcn_mfma_f32_16x16x32_bf16(afrag, bfrag, acc[nt], 0, 0, 0);
        }
    }
    // epilogue: C layout col=lane&15, row=(lane>>4)*4+reg
    float* outp = kind ? outv : outq;
    for (int nt = 0; nt < 4; nt++) {
        for (int r = 0; r < 4; r++) {
            int irow = i0 + mh * 16 + (lane >> 4) * 4 + r;
            int e = nt * 16 + (lane & 15);
            outp[(size_t)(b * N + irow) * 256 + h * 64 + e] = acc[nt][r];
        }
    }
}

// ---------------- K4: expmap0 for query (per-head) and value (concat) ----------------
__global__ void k_expmap(const float* __restrict__ outq, const float* __restrict__ outv,
                         float* __restrict__ query, float* __restrict__ sq,
                         float* __restrict__ val) {
    int p = blockIdx.x, t = threadIdx.x;
    int h = t >> 6, e = t & 63;
    float v = outq[(size_t)p * HD + t];
    float ss = v * v;
    for (int m = 32; m; m >>= 1) ss += __shfl_xor(ss, m);
    float n = fmaxf(sqrtf(ss), EPSF);
    float tn = tanhf(n);
    query[(size_t)p * HD + t] = v * (tn / n);
    if (e == 0) sq[h * BN + p] = tn * tn;

    float vv = outv[(size_t)p * HDV + t];
    float s2 = vv * vv;
    for (int m = 32; m; m >>= 1) s2 += __shfl_xor(s2, m);
    __shared__ float part[4];
    if (e == 0) part[h] = s2;
    __syncthreads();
    float tot = part[0] + part[1] + part[2] + part[3];
    float nv = fmaxf(sqrtf(tot), EPSF);
    float sclv = tanhf(nv) / nv;
    val[(size_t)p * HDV + t] = vv * sclv;
}

// ---------------- K5: scrambled pair-dist + tanh + head-mean -> m (pre-symmetrize) ----
// reshape(-1,B,N,N) closed form: h=m2%4, m=(n2%4)*256+m2/4, n=(b2*256+n2/4)%1024, b=2a+b2/4
__global__ __launch_bounds__(256) void k_att(const float* __restrict__ query,
        const float* __restrict__ sq, const float* __restrict__ rr,
        const float* __restrict__ tt, float* __restrict__ m_out) {
    int kc = blockIdx.x >> 1, mh = blockIdx.x & 1;
    int c = blockIdx.y >> 2, h = blockIdx.y & 3;
    int b2 = blockIdx.z;
    __shared__ float Xs[64][68];
    __shared__ float Ys[128][68];
    __shared__ float sqX[64], sqY[128];
    int t = threadIdx.x;
    int nstart = (b2 * 256 + kc * 64) & 1023;
    int mstart = c * 256 + mh * 128;
    int ti = t >> 4, tm = t & 15;
    float tacc[4][8] = {};
    for (int a = 0; a < 4; a++) {
        int b = 2 * a + (b2 >> 2);
        __syncthreads();
        {   // stage X: 64 rows x 64 dims
            int row = t >> 2, g = (t & 3) * 4;
            const float* src = query + (size_t)(b * N + nstart + row) * HD + h * 64;
            float4* dst = reinterpret_cast<float4*>(&Xs[row][0]);
            for (int u = 0; u < 4; u++) dst[g + u] = *reinterpret_cast<const float4*>(src + (g + u) * 4);
            if (t < 64) sqX[t] = sq[h * BN + b * N + nstart + t];
        }
        {   // stage Y: 128 rows x 64 dims
            int row = t >> 1, g = (t & 1) * 8;
            const float* src = query + (size_t)(b * N + mstart + row) * HD + h * 64;
            float4* dst = reinterpret_cast<float4*>(&Ys[row][0]);
            for (int u = 0; u < 8; u++) dst[g + u] = *reinterpret_cast<const float4*>(src + (g + u) * 4);
            if (t < 128) sqY[t] = sq[h * BN + b * N + mstart + t];
        }
        __syncthreads();
        float ra = rr[a], ta = tt[a];
        float dot[4][8] = {};
        for (int d4 = 0; d4 < 16; d4++) {
            float4 xv[4], yv[8];
            for (int ii = 0; ii < 4; ii++) xv[ii] = *reinterpret_cast<const float4*>(&Xs[ti + 16 * ii][d4 * 4]);
            for (int jj = 0; jj < 8; jj++) yv[jj] = *reinterpret_cast<const float4*>(&Ys[tm + 16 * jj][d4 * 4]);
            for (int ii = 0; ii < 4; ii++)
                for (int jj = 0; jj < 8; jj++) {
                    dot[ii][jj] = fmaf(xv[ii].x, yv[jj].x, dot[ii][jj]);
                    dot[ii][jj] = fmaf(xv[ii].y, yv[jj].y, dot[ii][jj]);
                    dot[ii][jj] = fmaf(xv[ii].z, yv[jj].z, dot[ii][jj]);
                    dot[ii][jj] = fmaf(xv[ii].w, yv[jj].w, dot[ii][jj]);
                }
        }
        for (int ii = 0; ii < 4; ii++) {
            float sx = sqX[ti + 16 * ii];
            for (int jj = 0; jj < 8; jj++) {
                float sy = sqY[tm + 16 * jj];
                float diff = fmaxf(sx + sy - 2.f * dot[ii][jj], 0.f);
                float den = fmaxf((1.f - sx) * (1.f - sy), EPSF);
                float z = fmaxf(1.f + 2.f * diff / den, 1.f + EPSF);
                float dist = __logf(z + sqrtf(z * z - 1.f));
                float uarg = (ra - dist) * ta;
                float ex = __expf(2.f * uarg);
                tacc[ii][jj] += 1.f - 2.f / (ex + 1.f);   // tanh, NaN-safe
            }
        }
    }
    for (int ii = 0; ii < 4; ii++) {
        int n2 = c + 4 * (kc * 64 + ti + 16 * ii);
        size_t base = ((size_t)b2 << 20) + ((size_t)n2 << 10);
        for (int jj = 0; jj < 8; jj++) {
            int mloc = mh * 128 + tm + 16 * jj;
            int m2 = 4 * mloc + h;
            m_out[base + m2] = 0.25f * tacc[ii][jj];
        }
    }
}

// ---------------- K6: in-place symmetrize on d_out att region ----------------
__global__ void k_sym(float* __restrict__ m) {
    int ti = blockIdx.x, tj = blockIdx.y, b = blockIdx.z;
    if (ti > tj) return;
    __shared__ float A[32][33], Bt[32][33];
    int t = threadIdx.x;
    int r = t >> 3, c4 = (t & 7) * 4;
    size_t baseA = ((size_t)b << 20) + (size_t)(ti * 32) * N + tj * 32;
    size_t baseB = ((size_t)b << 20) + (size_t)(tj * 32) * N + ti * 32;
    float4 ua = *reinterpret_cast<const float4*>(m + baseA + (size_t)r * N + c4);
    float4 ub = *reinterpret_cast<const float4*>(m + baseB + (size_t)r * N + c4);
    A[r][c4 + 0] = ua.x; A[r][c4 + 1] = ua.y; A[r][c4 + 2] = ua.z; A[r][c4 + 3] = ua.w;
    Bt[r][c4 + 0] = ub.x; Bt[r][c4 + 1] = ub.y; Bt[r][c4 + 2] = ub.z; Bt[r][c4 + 3] = ub.w;
    __syncthreads();
    for (int u = 0; u < 4; u++) {
        int cc = c4 + u;
        float oa = 0.5f * (A[r][cc] + Bt[cc][r]);
        float ob = 0.5f * (Bt[r][cc] + A[cc][r]);
        m[baseA + (size_t)r * N + cc] = oa;
        m[baseB + (size_t)r * N + cc] = ob;
    }
}

extern "C" void kernel_launch(void* const* d_in, const int* in_sizes, int n_in,
                              void* d_out, int out_size, void* d_ws, size_t ws_size,
                              hipStream_t stream) {
    const float* x   = (const float*)d_in[0];
    const float* adj = (const float*)d_in[1];
    const float* Wq  = (const float*)d_in[3];
    const float* aqs = (const float*)d_in[4];
    const float* aqd = (const float*)d_in[5];
    const float* Wv  = (const float*)d_in[6];
    const float* avs = (const float*)d_in[7];
    const float* avd = (const float*)d_in[8];
    const float* rr  = (const float*)d_in[9];
    const float* tt  = (const float*)d_in[10];

    float* ws = (float*)d_ws;
    float* s     = ws;                            // 8192
    float* Wc    = s + BN;                        // 131072
    float* hall  = Wc + 256 * COLS;               // 4194304
    float* esq   = hall + (size_t)BN * COLS;      // 32768 x4
    float* edq   = esq + BHN;
    float* esv   = edq + BHN;
    float* edv   = esv + BHN;
    float* stats = edv + BHN;                     // 4*BHN
    float* outq  = stats + 4 * BHN;               // 2097152
    float* outv  = outq + (size_t)BN * HD;        // 2097152
    float* query = outq;                          // in-place over outq (element-local)
    float* sq    = outv + (size_t)BN * HDV;       // 32768
    size_t need = (size_t)(sq + H * BN - ws) * sizeof(float);
    if (ws_size < need) return;                   // ws too small: bail visibly

    float* val  = (float*)d_out;
    float* matt = (float*)d_out + (size_t)BN * HDV;

    k_scale<<<BN / 4, 256, 0, stream>>>(x, s);
    k_wcat<<<(256 * COLS) / 256, 256, 0, stream>>>(Wq, Wv, Wc);
    k_gemm<<<dim3(BN / 64, COLS / 64), 256, 0, stream>>>(x, s, Wc, hall);
    k_esed<<<BN, 256, 0, stream>>>(hall, aqs, aqd, avs, avd, esq, edq, esv, edv);
    k_stats<<<BHN, 128, 0, stream>>>(adj, esq, edq, esv, edv, stats);
    k_aggr<<<dim3(32, H, B), 256, 0, stream>>>(adj, hall, esq, edq, esv, edv, stats, outq, outv);
    k_expmap<<<BN, 256, 0, stream>>>(outq, outv, query, sq, val);
    k_att<<<dim3(8, 16, 8), 256, 0, stream>>>(query, sq, rr, tt, matt);
    k_sym<<<dim3(32, 32, 8), 256, 0, stream>>>(matt);
}

// Round 4
// 327.572 us; speedup vs baseline: 1.8838x; 1.0525x over previous
//
#include <hip/hip_runtime.h>
#include <hip/hip_bf16.h>
#include <math.h>

#define DEV __device__ __forceinline__

constexpr int B = 8, N = 1024, DIN = 256, H = 4, DATT = 64, DV = 64;
constexpr int BN = B * N;             // 8192
constexpr int HD = H * DATT;          // 256
constexpr int HDV = H * DV;           // 256
constexpr int COLS = HD + HDV;        // 512
constexpr int BHN = B * H * N;        // 32768
constexpr float EPSF = 1e-7f;

using short8 = __attribute__((ext_vector_type(8))) short;
using f32x4  = __attribute__((ext_vector_type(4))) float;

DEV unsigned short f2bf(float f) {
    __hip_bfloat16 h = __float2bfloat16(f);
    return *reinterpret_cast<unsigned short*>(&h);
}
DEV float bfu2f(unsigned short u) { return __uint_as_float(((unsigned)u) << 16); }

// ---------------- K1: logmap0 row scale: s = artanh(nc)/nc ----------------
__global__ void k_scale(const float* __restrict__ x, float* __restrict__ s) {
    int p = blockIdx.x * 4 + (threadIdx.x >> 6);
    int l = threadIdx.x & 63;
    const float4* xr = reinterpret_cast<const float4*>(x + (size_t)p * DIN);
    float4 u = xr[l];
    float ss = u.x * u.x + u.y * u.y + u.z * u.z + u.w * u.w;
    for (int m = 32; m; m >>= 1) ss += __shfl_xor(ss, m);
    if (l == 0) {
        float n = sqrtf(ss);
        n = fminf(fmaxf(n, EPSF), 1.0f - 1e-5f);
        float at = 0.5f * __logf((1.f + n) / (1.f - n));
        s[p] = at / n;
    }
}

// ---------------- K0: build Wcat [256][512] f32 (Wq | Wv) ----------------
__global__ void k_wcat(const float* __restrict__ Wq, const float* __restrict__ Wv,
                       float* __restrict__ Wc) {
    int idx = blockIdx.x * 256 + threadIdx.x;   // < 256*512
    int k = idx >> 9, c = idx & 511;
    int cc = c & 255;
    int h = cc >> 6, e = cc & 63;
    const float* src = (c < HD) ? Wq : Wv;
    Wc[idx] = src[(h * DIN + k) * 64 + e];
}

// ---------------- K2: GEMM h_all[8192][512] = (s*x)[8192][256] @ Wc ----------------
__global__ __launch_bounds__(256) void k_gemm(const float* __restrict__ x,
                                              const float* __restrict__ s,
                                              const float* __restrict__ Wc,
                                              float* __restrict__ hall) {
    __shared__ float As[16][68];
    __shared__ float Bs[16][68];
    int bm = blockIdx.x, bn = blockIdx.y;
    int tid = threadIdx.x;
    int ty = tid >> 4, tx = tid & 15;
    float acc[4][4] = {};
    int rowbase = bm * 64, colbase = bn * 64;
    int am = tid >> 2;
    int ak = (tid & 3) * 4;
    float sc = s[rowbase + am];
    for (int kt = 0; kt < DIN; kt += 16) {
        float4 u = *reinterpret_cast<const float4*>(x + (size_t)(rowbase + am) * DIN + kt + ak);
        As[ak + 0][am] = u.x * sc;
        As[ak + 1][am] = u.y * sc;
        As[ak + 2][am] = u.z * sc;
        As[ak + 3][am] = u.w * sc;
        int bk = tid >> 4, bc = (tid & 15) * 4;
        float4 w4 = *reinterpret_cast<const float4*>(Wc + (size_t)(kt + bk) * COLS + colbase + bc);
        *reinterpret_cast<float4*>(&Bs[bk][bc]) = w4;
        __syncthreads();
        for (int k = 0; k < 16; k++) {
            float4 a4 = *reinterpret_cast<const float4*>(&As[k][ty * 4]);
            float4 b4 = *reinterpret_cast<const float4*>(&Bs[k][tx * 4]);
            float av[4] = {a4.x, a4.y, a4.z, a4.w};
            float bv[4] = {b4.x, b4.y, b4.z, b4.w};
            for (int i = 0; i < 4; i++)
                for (int j = 0; j < 4; j++) acc[i][j] = fmaf(av[i], bv[j], acc[i][j]);
        }
        __syncthreads();
    }
    for (int i = 0; i < 4; i++) {
        float4 o = make_float4(acc[i][0], acc[i][1], acc[i][2], acc[i][3]);
        *reinterpret_cast<float4*>(hall + (size_t)(rowbase + ty * 4 + i) * COLS + colbase + tx * 4) = o;
    }
}

// ---------------- K2b: es/ed dot products, layout [B][H][N] ----------------
__global__ void k_esed(const float* __restrict__ hall, const float* __restrict__ aqs,
                       const float* __restrict__ aqd, const float* __restrict__ avs,
                       const float* __restrict__ avd, float* __restrict__ esq,
                       float* __restrict__ edq, float* __restrict__ esv,
                       float* __restrict__ edv) {
    int p = blockIdx.x;
    int h = threadIdx.x >> 6, e = threadIdx.x & 63;
    float hq = hall[(size_t)p * COLS + h * 64 + e];
    float hv = hall[(size_t)p * COLS + 256 + h * 64 + e];
    float v1 = hq * aqs[h * 64 + e];
    float v2 = hq * aqd[h * 64 + e];
    float v3 = hv * avs[h * 64 + e];
    float v4 = hv * avd[h * 64 + e];
    for (int m = 32; m; m >>= 1) {
        v1 += __shfl_xor(v1, m); v2 += __shfl_xor(v2, m);
        v3 += __shfl_xor(v3, m); v4 += __shfl_xor(v4, m);
    }
    if (e == 0) {
        int b = p >> 10, n = p & 1023;
        int o = (b * H + h) * N + n;
        esq[o] = v1; edq[o] = v2; esv[o] = v3; edv[o] = v4;
    }
}

// ---------------- K3a: per-row softmax stats (max,sum) for q and v ----------------
__global__ void k_stats(const float* __restrict__ adj, const float* __restrict__ esq,
                        const float* __restrict__ edq, const float* __restrict__ esv,
                        const float* __restrict__ edv, float* __restrict__ stats) {
    int bid = blockIdx.x;                 // (b*H + h)*N + i
    int i = bid & 1023;
    int bh = bid >> 10;
    int b = bh >> 2;
    int t = threadIdx.x;                  // 128 threads, 8 j each
    float esqi = esq[bid], esvi = esv[bid];
    const float* arow = adj + (size_t)(b * N + i) * N + t * 8;
    const float* edqr = edq + (size_t)bh * N + t * 8;
    const float* edvr = edv + (size_t)bh * N + t * 8;
    float4 a0 = *reinterpret_cast<const float4*>(arow);
    float4 a1 = *reinterpret_cast<const float4*>(arow + 4);
    float am[8] = {a0.x, a0.y, a0.z, a0.w, a1.x, a1.y, a1.z, a1.w};
    float4 q0 = *reinterpret_cast<const float4*>(edqr);
    float4 q1 = *reinterpret_cast<const float4*>(edqr + 4);
    float4 w0 = *reinterpret_cast<const float4*>(edvr);
    float4 w1 = *reinterpret_cast<const float4*>(edvr + 4);
    float edqv[8] = {q0.x, q0.y, q0.z, q0.w, q1.x, q1.y, q1.z, q1.w};
    float edvv[8] = {w0.x, w0.y, w0.z, w0.w, w1.x, w1.y, w1.z, w1.w};
    float eq[8], ev[8];
    float mq = -1e30f, mv = -1e30f;
    for (int j = 0; j < 8; j++) {
        bool msk = am[j] > 0.f;
        float q = esqi + edqv[j]; q = fmaxf(q, 0.2f * q);
        float v = esvi + edvv[j]; v = fmaxf(v, 0.2f * v);
        eq[j] = msk ? q : -1e30f;
        ev[j] = msk ? v : -1e30f;
        mq = fmaxf(mq, eq[j]); mv = fmaxf(mv, ev[j]);
    }
    __shared__ float red[2][2];
    __shared__ float red2[2][2];
    for (int m = 32; m; m >>= 1) { mq = fmaxf(mq, __shfl_xor(mq, m)); mv = fmaxf(mv, __shfl_xor(mv, m)); }
    int w = t >> 6;
    if ((t & 63) == 0) { red[w][0] = mq; red[w][1] = mv; }
    __syncthreads();
    mq = fmaxf(red[0][0], red[1][0]);
    mv = fmaxf(red[0][1], red[1][1]);
    float sq_ = 0.f, sv_ = 0.f;
    for (int j = 0; j < 8; j++) { sq_ += __expf(eq[j] - mq); sv_ += __expf(ev[j] - mv); }
    for (int m = 32; m; m >>= 1) { sq_ += __shfl_xor(sq_, m); sv_ += __shfl_xor(sv_, m); }
    if ((t & 63) == 0) { red2[w][0] = sq_; red2[w][1] = sv_; }
    __syncthreads();
    if (t == 0) {
        stats[bid] = mq;
        stats[BHN + bid] = red2[0][0] + red2[1][0];
        stats[2 * BHN + bid] = mv;
        stats[3 * BHN + bid] = red2[0][1] + red2[1][1];
    }
}

// ---------------- K3b: MFMA GAT aggregation (q and v fused) ----------------
__global__ __launch_bounds__(256) void k_aggr(const float* __restrict__ adj,
        const float* __restrict__ hall, const float* __restrict__ esq,
        const float* __restrict__ edq, const float* __restrict__ esv,
        const float* __restrict__ edv, const float* __restrict__ stats,
        float* __restrict__ outq, float* __restrict__ outv) {
    int it = blockIdx.x, h = blockIdx.y, b = blockIdx.z;
    int i0 = it * 32;
    int t = threadIdx.x;
    int lane = t & 63, wv = t >> 6;
    int mh = wv & 1, kind = wv >> 1;          // 0=q, 1=v
    int bh = b * H + h;

    __shared__ __align__(16) unsigned short hT[128][40];  // [e][j] bf16; 80B rows

    int i = i0 + mh * 16 + (lane & 15);
    int bi = bh * N + i;
    const float* es_p = kind ? esv : esq;
    const float* ed_p = kind ? edv : edq;
    float es_i = es_p[bi];
    float m_i  = stats[2 * kind * BHN + bi];
    float is_i = 1.f / stats[(2 * kind + 1) * BHN + bi];
    const float* adjrow = adj + (size_t)(b * N + i) * N;
    const float* edrow  = ed_p + (size_t)bh * N;
    int klo = lane >> 4;

    int jp = t & 15;
    int eg = t >> 4;
    int ebase = eg * 8;
    int col0 = (ebase < 64) ? (h * 64 + ebase) : (256 + h * 64 + (ebase - 64));

    f32x4 acc[4] = {};
    int erow = kind * 64 + (lane & 15);

    for (int jt = 0; jt < 32; jt++) {
        int j0 = jt * 32;
        float4 a0 = *reinterpret_cast<const float4*>(adjrow + j0 + klo * 8);
        float4 a1 = *reinterpret_cast<const float4*>(adjrow + j0 + klo * 8 + 4);
        float4 e0 = *reinterpret_cast<const float4*>(edrow + j0 + klo * 8);
        float4 e1 = *reinterpret_cast<const float4*>(edrow + j0 + klo * 8 + 4);
        const float* r0 = hall + (size_t)(b * N + j0 + 2 * jp) * COLS + col0;
        float4 f0a = *reinterpret_cast<const float4*>(r0);
        float4 f0b = *reinterpret_cast<const float4*>(r0 + 4);
        float4 f1a = *reinterpret_cast<const float4*>(r0 + COLS);
        float4 f1b = *reinterpret_cast<const float4*>(r0 + COLS + 4);
        __syncthreads();
        {
            float lof[8] = {f0a.x, f0a.y, f0a.z, f0a.w, f0b.x, f0b.y, f0b.z, f0b.w};
            float hif[8] = {f1a.x, f1a.y, f1a.z, f1a.w, f1b.x, f1b.y, f1b.z, f1b.w};
            for (int uu = 0; uu < 8; uu++) {
                int u = (uu + eg) & 7;
                unsigned int wword = (unsigned int)f2bf(lof[u]) |
                                     ((unsigned int)f2bf(hif[u]) << 16);
                reinterpret_cast<unsigned int*>(&hT[ebase + u][0])[jp] = wword;
            }
        }
        float av[8] = {a0.x, a0.y, a0.z, a0.w, a1.x, a1.y, a1.z, a1.w};
        float ev[8] = {e0.x, e0.y, e0.z, e0.w, e1.x, e1.y, e1.z, e1.w};
        short8 afrag;
        for (int u = 0; u < 8; u++) {
            float q = es_i + ev[u];
            q = fmaxf(q, 0.2f * q);
            float wgt = (av[u] > 0.f) ? __expf(q - m_i) * is_i : 0.f;
            afrag[u] = (short)f2bf(wgt);
        }
        __syncthreads();
        for (int nt = 0; nt < 4; nt++) {
            short8 bfrag = *reinterpret_cast<const short8*>(&hT[erow + nt * 16][klo * 8]);
            acc[nt] = __builtin_amdgcn_mfma_f32_16x16x32_bf16(afrag, bfrag, acc[nt], 0, 0, 0);
        }
    }
    float* outp = kind ? outv : outq;
    for (int nt = 0; nt < 4; nt++) {
        for (int r = 0; r < 4; r++) {
            int irow = i0 + mh * 16 + (lane >> 4) * 4 + r;
            int e = nt * 16 + (lane & 15);
            outp[(size_t)(b * N + irow) * 256 + h * 64 + e] = acc[nt][r];
        }
    }
}

// ---------------- K4: expmap0 for query (per-head) and value (concat) ----------------
__global__ void k_expmap(const float* __restrict__ outq, const float* __restrict__ outv,
                         float* __restrict__ query, float* __restrict__ sq,
                         float* __restrict__ val) {
    int p = blockIdx.x, t = threadIdx.x;
    int h = t >> 6, e = t & 63;
    float v = outq[(size_t)p * HD + t];
    float ss = v * v;
    for (int m = 32; m; m >>= 1) ss += __shfl_xor(ss, m);
    float n = fmaxf(sqrtf(ss), EPSF);
    float tn = tanhf(n);
    query[(size_t)p * HD + t] = v * (tn / n);
    if (e == 0) sq[h * BN + p] = tn * tn;

    float vv = outv[(size_t)p * HDV + t];
    float s2 = vv * vv;
    for (int m = 32; m; m >>= 1) s2 += __shfl_xor(s2, m);
    __shared__ float part[4];
    if (e == 0) part[h] = s2;
    __syncthreads();
    float tot = part[0] + part[1] + part[2] + part[3];
    float nv = fmaxf(sqrtf(tot), EPSF);
    float sclv = tanhf(nv) / nv;
    val[(size_t)p * HDV + t] = vv * sclv;
}

// ---------------- K5: MFMA pair-dist (split-bf16 hi/lo) + tanh + head-mean ----------
// reshape(-1,B,N,N) closed form: h=m2%4, m=(n2%4)*256+m2/4, n=(b2*256+n2/4)%1024, b=2a+b2/4
// LDS: Xh/Xl[64][64] bf16, Yh/Yl[128][64] bf16, rows 128B -> XOR-swizzle 16B-chunk by (row&7).
DEV int swzX(int row, int ch) { return row * 64 + ((ch ^ (row & 7)) * 8); }  // ushort index

DEV void att_split2(float v, short& hs, short& ls) {
    unsigned short hu = f2bf(v);
    float hf = bfu2f(hu);
    hs = (short)hu;
    ls = (short)f2bf(v - hf);
}

__global__ __launch_bounds__(256) void k_att(const float* __restrict__ query,
        const float* __restrict__ sq, const float* __restrict__ rr,
        const float* __restrict__ tt, float* __restrict__ m_out) {
    int kc = blockIdx.x >> 1, xh = blockIdx.x & 1;
    int c = blockIdx.y >> 2, h = blockIdx.y & 3;
    int b2 = blockIdx.z;
    int t = threadIdx.x;
    int l = t & 63, w = t >> 6;

    __shared__ __align__(16) unsigned short Xh[64 * 64], Xl[64 * 64];
    __shared__ __align__(16) unsigned short Yh[128 * 64], Yl[128 * 64];
    __shared__ float sqX[64], sqY[128];

    int nstart = (b2 * 256 + kc * 64) & 1023;
    int mstart = c * 256 + xh * 128;

    int rowX = t >> 2, pX = t & 3;       // X stage: 16 d-values at pX*16
    int rowY = t >> 1, pY = t & 1;       // Y stage: 32 d-values at pY*32

    float4 RX[4], RY[8];
    float rsx = 0.f, rsy = 0.f;
    float tacc[8][4] = {};

    {   // prologue prefetch (a = 0)
        int b = (b2 >> 2);
        const float4* sx4 = reinterpret_cast<const float4*>(query + (size_t)(b * N + nstart + rowX) * HD + h * 64);
        #pragma unroll
        for (int u = 0; u < 4; u++) RX[u] = sx4[pX * 4 + u];
        const float4* sy4 = reinterpret_cast<const float4*>(query + (size_t)(b * N + mstart + rowY) * HD + h * 64);
        #pragma unroll
        for (int u = 0; u < 8; u++) RY[u] = sy4[pY * 8 + u];
        if (t < 64)  rsx = sq[h * BN + b * N + nstart + t];
        if (t < 128) rsy = sq[h * BN + b * N + mstart + t];
    }

    #pragma unroll
    for (int a = 0; a < 4; a++) {
        __syncthreads();                  // prev compute done + prefetch loads drained
        {   // stage: split f32 -> bf16 hi/lo, swizzled writes
            short8 hx0, hx1, lx0, lx1;
            #pragma unroll
            for (int u = 0; u < 4; u++) {
                float vv[4] = {RX[u].x, RX[u].y, RX[u].z, RX[u].w};
                #pragma unroll
                for (int q = 0; q < 4; q++) {
                    short hs, ls; att_split2(vv[q], hs, ls);
                    if (u < 2) { hx0[u * 4 + q] = hs; lx0[u * 4 + q] = ls; }
                    else       { hx1[(u - 2) * 4 + q] = hs; lx1[(u - 2) * 4 + q] = ls; }
                }
            }
            *reinterpret_cast<short8*>(&Xh[swzX(rowX, pX * 2)])     = hx0;
            *reinterpret_cast<short8*>(&Xh[swzX(rowX, pX * 2 + 1)]) = hx1;
            *reinterpret_cast<short8*>(&Xl[swzX(rowX, pX * 2)])     = lx0;
            *reinterpret_cast<short8*>(&Xl[swzX(rowX, pX * 2 + 1)]) = lx1;
            #pragma unroll
            for (int q = 0; q < 4; q++) {
                short8 hy, ly;
                float v0[4] = {RY[2 * q].x, RY[2 * q].y, RY[2 * q].z, RY[2 * q].w};
                float v1[4] = {RY[2 * q + 1].x, RY[2 * q + 1].y, RY[2 * q + 1].z, RY[2 * q + 1].w};
                #pragma unroll
                for (int e = 0; e < 4; e++) {
                    short hs, ls; att_split2(v0[e], hs, ls);
                    hy[e] = hs; ly[e] = ls;
                    att_split2(v1[e], hs, ls);
                    hy[4 + e] = hs; ly[4 + e] = ls;
                }
                *reinterpret_cast<short8*>(&Yh[swzX(rowY, pY * 4 + q)]) = hy;
                *reinterpret_cast<short8*>(&Yl[swzX(rowY, pY * 4 + q)]) = ly;
            }
            if (t < 64)  sqX[t] = rsx;
            if (t < 128) sqY[t] = rsy;
        }
        __syncthreads();                  // staging visible; no vmem outstanding
        if (a < 3) {                      // T14: prefetch a+1 under compute
            int b = 2 * (a + 1) + (b2 >> 2);
            const float4* sx4 = reinterpret_cast<const float4*>(query + (size_t)(b * N + nstart + rowX) * HD + h * 64);
            #pragma unroll
            for (int u = 0; u < 4; u++) RX[u] = sx4[pX * 4 + u];
            const float4* sy4 = reinterpret_cast<const float4*>(query + (size_t)(b * N + mstart + rowY) * HD + h * 64);
            #pragma unroll
            for (int u = 0; u < 8; u++) RY[u] = sy4[pY * 8 + u];
            if (t < 64)  rsx = sq[h * BN + b * N + nstart + t];
            if (t < 128) rsy = sq[h * BN + b * N + mstart + t];
        }
        // A-fragments: wave w owns X rows w*16..+15
        short8 Ah[2], Al[2];
        #pragma unroll
        for (int kk = 0; kk < 2; kk++) {
            int rx = w * 16 + (l & 15);
            int idx = swzX(rx, kk * 4 + (l >> 4));
            Ah[kk] = *reinterpret_cast<const short8*>(&Xh[idx]);
            Al[kk] = *reinterpret_cast<const short8*>(&Xl[idx]);
        }
        float ra = rr[a], ta = tt[a];
        #pragma unroll
        for (int nt = 0; nt < 8; nt++) {
            int ry = nt * 16 + (l & 15);
            f32x4 acc = {};
            #pragma unroll
            for (int kk = 0; kk < 2; kk++) {
                int idy = swzX(ry, kk * 4 + (l >> 4));
                short8 Bh = *reinterpret_cast<const short8*>(&Yh[idy]);
                short8 Bl = *reinterpret_cast<const short8*>(&Yl[idy]);
                acc = __builtin_amdgcn_mfma_f32_16x16x32_bf16(Ah[kk], Bh, acc, 0, 0, 0);
                acc = __builtin_amdgcn_mfma_f32_16x16x32_bf16(Ah[kk], Bl, acc, 0, 0, 0);
                acc = __builtin_amdgcn_mfma_f32_16x16x32_bf16(Al[kk], Bh, acc, 0, 0, 0);
            }
            float sy = sqY[nt * 16 + (l & 15)];
            #pragma unroll
            for (int r = 0; r < 4; r++) {
                float sx = sqX[w * 16 + (l >> 4) * 4 + r];
                float dot = acc[r];
                float diff = fmaxf(sx + sy - 2.f * dot, 0.f);
                float den = fmaxf((1.f - sx) * (1.f - sy), EPSF);
                float z = fmaxf(1.f + 2.f * diff / den, 1.f + EPSF);
                float dist = __logf(z + sqrtf(z * z - 1.f));
                float uarg = (ra - dist) * ta;
                float ex = __expf(2.f * uarg);
                tacc[nt][r] += 1.f - 2.f / (ex + 1.f);   // tanh, NaN-safe
            }
        }
    }
    // write-out (scrambled reshape positions)
    #pragma unroll
    for (int nt = 0; nt < 8; nt++) {
        #pragma unroll
        for (int r = 0; r < 4; r++) {
            int n_local = w * 16 + (l >> 4) * 4 + r;
            int n2 = c + 4 * (kc * 64 + n_local);
            int mloc = xh * 128 + nt * 16 + (l & 15);
            int m2 = 4 * mloc + h;
            m_out[((size_t)b2 << 20) + ((size_t)n2 << 10) + m2] = 0.25f * tacc[nt][r];
        }
    }
}

// ---------------- K6: in-place symmetrize on d_out att region ----------------
__global__ void k_sym(float* __restrict__ m) {
    int ti = blockIdx.x, tj = blockIdx.y, b = blockIdx.z;
    if (ti > tj) return;
    __shared__ float A[32][33], Bt[32][33];
    int t = threadIdx.x;
    int r = t >> 3, c4 = (t & 7) * 4;
    size_t baseA = ((size_t)b << 20) + (size_t)(ti * 32) * N + tj * 32;
    size_t baseB = ((size_t)b << 20) + (size_t)(tj * 32) * N + ti * 32;
    float4 ua = *reinterpret_cast<const float4*>(m + baseA + (size_t)r * N + c4);
    float4 ub = *reinterpret_cast<const float4*>(m + baseB + (size_t)r * N + c4);
    A[r][c4 + 0] = ua.x; A[r][c4 + 1] = ua.y; A[r][c4 + 2] = ua.z; A[r][c4 + 3] = ua.w;
    Bt[r][c4 + 0] = ub.x; Bt[r][c4 + 1] = ub.y; Bt[r][c4 + 2] = ub.z; Bt[r][c4 + 3] = ub.w;
    __syncthreads();
    for (int u = 0; u < 4; u++) {
        int cc = c4 + u;
        float oa = 0.5f * (A[r][cc] + Bt[cc][r]);
        float ob = 0.5f * (Bt[r][cc] + A[cc][r]);
        m[baseA + (size_t)r * N + cc] = oa;
        m[baseB + (size_t)r * N + cc] = ob;
    }
}

extern "C" void kernel_launch(void* const* d_in, const int* in_sizes, int n_in,
                              void* d_out, int out_size, void* d_ws, size_t ws_size,
                              hipStream_t stream) {
    const float* x   = (const float*)d_in[0];
    const float* adj = (const float*)d_in[1];
    const float* Wq  = (const float*)d_in[3];
    const float* aqs = (const float*)d_in[4];
    const float* aqd = (const float*)d_in[5];
    const float* Wv  = (const float*)d_in[6];
    const float* avs = (const float*)d_in[7];
    const float* avd = (const float*)d_in[8];
    const float* rr  = (const float*)d_in[9];
    const float* tt  = (const float*)d_in[10];

    float* ws = (float*)d_ws;
    float* s     = ws;                            // 8192
    float* Wc    = s + BN;                        // 131072
    float* hall  = Wc + 256 * COLS;               // 4194304
    float* esq   = hall + (size_t)BN * COLS;      // 32768 x4
    float* edq   = esq + BHN;
    float* esv   = edq + BHN;
    float* edv   = esv + BHN;
    float* stats = edv + BHN;                     // 4*BHN
    float* outq  = stats + 4 * BHN;               // 2097152
    float* outv  = outq + (size_t)BN * HD;        // 2097152
    float* query = outq;                          // in-place over outq (element-local)
    float* sq    = outv + (size_t)BN * HDV;       // 32768
    size_t need = (size_t)(sq + H * BN - ws) * sizeof(float);
    if (ws_size < need) return;                   // ws too small: bail visibly

    float* val  = (float*)d_out;
    float* matt = (float*)d_out + (size_t)BN * HDV;

    k_scale<<<BN / 4, 256, 0, stream>>>(x, s);
    k_wcat<<<(256 * COLS) / 256, 256, 0, stream>>>(Wq, Wv, Wc);
    k_gemm<<<dim3(BN / 64, COLS / 64), 256, 0, stream>>>(x, s, Wc, hall);
    k_esed<<<BN, 256, 0, stream>>>(hall, aqs, aqd, avs, avd, esq, edq, esv, edv);
    k_stats<<<BHN, 128, 0, stream>>>(adj, esq, edq, esv, edv, stats);
    k_aggr<<<dim3(32, H, B), 256, 0, stream>>>(adj, hall, esq, edq, esv, edv, stats, outq, outv);
    k_expmap<<<BN, 256, 0, stream>>>(outq, outv, query, sq, val);
    k_att<<<dim3(8, 16, 8), 256, 0, stream>>>(query, sq, rr, tt, matt);
    k_sym<<<dim3(32, 32, 8), 256, 0, stream>>>(matt);
}

// Round 5
// 282.526 us; speedup vs baseline: 2.1841x; 1.1594x over previous
//
#include <hip/hip_runtime.h>
#include <hip/hip_bf16.h>
#include <math.h>

#define DEV __device__ __forceinline__

constexpr int B = 8, N = 1024, DIN = 256, H = 4, DATT = 64, DV = 64;
constexpr int BN = B * N;             // 8192
constexpr int HD = H * DATT;          // 256
constexpr int HDV = H * DV;           // 256
constexpr int COLS = HD + HDV;        // 512
constexpr int BHN = B * H * N;        // 32768
constexpr float EPSF = 1e-7f;

using short8 = __attribute__((ext_vector_type(8))) short;
using f32x4  = __attribute__((ext_vector_type(4))) float;

DEV unsigned short f2bf(float f) {
    __hip_bfloat16 h = __float2bfloat16(f);
    return *reinterpret_cast<unsigned short*>(&h);
}
DEV float bfu2f(unsigned short u) { return __uint_as_float(((unsigned)u) << 16); }

// ---------------- K1: logmap0 row scale: s = artanh(nc)/nc ----------------
__global__ void k_scale(const float* __restrict__ x, float* __restrict__ s) {
    int p = blockIdx.x * 4 + (threadIdx.x >> 6);
    int l = threadIdx.x & 63;
    const float4* xr = reinterpret_cast<const float4*>(x + (size_t)p * DIN);
    float4 u = xr[l];
    float ss = u.x * u.x + u.y * u.y + u.z * u.z + u.w * u.w;
    for (int m = 32; m; m >>= 1) ss += __shfl_xor(ss, m);
    if (l == 0) {
        float n = sqrtf(ss);
        n = fminf(fmaxf(n, EPSF), 1.0f - 1e-5f);
        float at = 0.5f * __logf((1.f + n) / (1.f - n));
        s[p] = at / n;
    }
}

// ---------------- K0: build Wcat [256][512] f32 (Wq | Wv) ----------------
__global__ void k_wcat(const float* __restrict__ Wq, const float* __restrict__ Wv,
                       float* __restrict__ Wc) {
    int idx = blockIdx.x * 256 + threadIdx.x;   // < 256*512
    int k = idx >> 9, c = idx & 511;
    int cc = c & 255;
    int h = cc >> 6, e = cc & 63;
    const float* src = (c < HD) ? Wq : Wv;
    Wc[idx] = src[(h * DIN + k) * 64 + e];
}

// ---------------- K2: GEMM h_all[8192][512] = (s*x)[8192][256] @ Wc ----------------
__global__ __launch_bounds__(256) void k_gemm(const float* __restrict__ x,
                                              const float* __restrict__ s,
                                              const float* __restrict__ Wc,
                                              float* __restrict__ hall) {
    __shared__ float As[16][68];
    __shared__ float Bs[16][68];
    int bm = blockIdx.x, bn = blockIdx.y;
    int tid = threadIdx.x;
    int ty = tid >> 4, tx = tid & 15;
    float acc[4][4] = {};
    int rowbase = bm * 64, colbase = bn * 64;
    int am = tid >> 2;
    int ak = (tid & 3) * 4;
    float sc = s[rowbase + am];
    for (int kt = 0; kt < DIN; kt += 16) {
        float4 u = *reinterpret_cast<const float4*>(x + (size_t)(rowbase + am) * DIN + kt + ak);
        As[ak + 0][am] = u.x * sc;
        As[ak + 1][am] = u.y * sc;
        As[ak + 2][am] = u.z * sc;
        As[ak + 3][am] = u.w * sc;
        int bk = tid >> 4, bc = (tid & 15) * 4;
        float4 w4 = *reinterpret_cast<const float4*>(Wc + (size_t)(kt + bk) * COLS + colbase + bc);
        *reinterpret_cast<float4*>(&Bs[bk][bc]) = w4;
        __syncthreads();
        for (int k = 0; k < 16; k++) {
            float4 a4 = *reinterpret_cast<const float4*>(&As[k][ty * 4]);
            float4 b4 = *reinterpret_cast<const float4*>(&Bs[k][tx * 4]);
            float av[4] = {a4.x, a4.y, a4.z, a4.w};
            float bv[4] = {b4.x, b4.y, b4.z, b4.w};
            for (int i = 0; i < 4; i++)
                for (int j = 0; j < 4; j++) acc[i][j] = fmaf(av[i], bv[j], acc[i][j]);
        }
        __syncthreads();
    }
    for (int i = 0; i < 4; i++) {
        float4 o = make_float4(acc[i][0], acc[i][1], acc[i][2], acc[i][3]);
        *reinterpret_cast<float4*>(hall + (size_t)(rowbase + ty * 4 + i) * COLS + colbase + tx * 4) = o;
    }
}

// ---------------- K2b: es/ed dot products, layout [B][H][N] ----------------
__global__ void k_esed(const float* __restrict__ hall, const float* __restrict__ aqs,
                       const float* __restrict__ aqd, const float* __restrict__ avs,
                       const float* __restrict__ avd, float* __restrict__ esq,
                       float* __restrict__ edq, float* __restrict__ esv,
                       float* __restrict__ edv) {
    int p = blockIdx.x;
    int h = threadIdx.x >> 6, e = threadIdx.x & 63;
    float hq = hall[(size_t)p * COLS + h * 64 + e];
    float hv = hall[(size_t)p * COLS + 256 + h * 64 + e];
    float v1 = hq * aqs[h * 64 + e];
    float v2 = hq * aqd[h * 64 + e];
    float v3 = hv * avs[h * 64 + e];
    float v4 = hv * avd[h * 64 + e];
    for (int m = 32; m; m >>= 1) {
        v1 += __shfl_xor(v1, m); v2 += __shfl_xor(v2, m);
        v3 += __shfl_xor(v3, m); v4 += __shfl_xor(v4, m);
    }
    if (e == 0) {
        int b = p >> 10, n = p & 1023;
        int o = (b * H + h) * N + n;
        esq[o] = v1; edq[o] = v2; esv[o] = v3; edv[o] = v4;
    }
}

// ---------------- K3a: per-row softmax stats (max,sum) for q and v ----------------
__global__ void k_stats(const float* __restrict__ adj, const float* __restrict__ esq,
                        const float* __restrict__ edq, const float* __restrict__ esv,
                        const float* __restrict__ edv, float* __restrict__ stats) {
    int bid = blockIdx.x;                 // (b*H + h)*N + i
    int i = bid & 1023;
    int bh = bid >> 10;
    int b = bh >> 2;
    int t = threadIdx.x;                  // 128 threads, 8 j each
    float esqi = esq[bid], esvi = esv[bid];
    const float* arow = adj + (size_t)(b * N + i) * N + t * 8;
    const float* edqr = edq + (size_t)bh * N + t * 8;
    const float* edvr = edv + (size_t)bh * N + t * 8;
    float4 a0 = *reinterpret_cast<const float4*>(arow);
    float4 a1 = *reinterpret_cast<const float4*>(arow + 4);
    float am[8] = {a0.x, a0.y, a0.z, a0.w, a1.x, a1.y, a1.z, a1.w};
    float4 q0 = *reinterpret_cast<const float4*>(edqr);
    float4 q1 = *reinterpret_cast<const float4*>(edqr + 4);
    float4 w0 = *reinterpret_cast<const float4*>(edvr);
    float4 w1 = *reinterpret_cast<const float4*>(edvr + 4);
    float edqv[8] = {q0.x, q0.y, q0.z, q0.w, q1.x, q1.y, q1.z, q1.w};
    float edvv[8] = {w0.x, w0.y, w0.z, w0.w, w1.x, w1.y, w1.z, w1.w};
    float eq[8], ev[8];
    float mq = -1e30f, mv = -1e30f;
    for (int j = 0; j < 8; j++) {
        bool msk = am[j] > 0.f;
        float q = esqi + edqv[j]; q = fmaxf(q, 0.2f * q);
        float v = esvi + edvv[j]; v = fmaxf(v, 0.2f * v);
        eq[j] = msk ? q : -1e30f;
        ev[j] = msk ? v : -1e30f;
        mq = fmaxf(mq, eq[j]); mv = fmaxf(mv, ev[j]);
    }
    __shared__ float red[2][2];
    __shared__ float red2[2][2];
    for (int m = 32; m; m >>= 1) { mq = fmaxf(mq, __shfl_xor(mq, m)); mv = fmaxf(mv, __shfl_xor(mv, m)); }
    int w = t >> 6;
    if ((t & 63) == 0) { red[w][0] = mq; red[w][1] = mv; }
    __syncthreads();
    mq = fmaxf(red[0][0], red[1][0]);
    mv = fmaxf(red[0][1], red[1][1]);
    float sq_ = 0.f, sv_ = 0.f;
    for (int j = 0; j < 8; j++) { sq_ += __expf(eq[j] - mq); sv_ += __expf(ev[j] - mv); }
    for (int m = 32; m; m >>= 1) { sq_ += __shfl_xor(sq_, m); sv_ += __shfl_xor(sv_, m); }
    if ((t & 63) == 0) { red2[w][0] = sq_; red2[w][1] = sv_; }
    __syncthreads();
    if (t == 0) {
        stats[bid] = mq;
        stats[BHN + bid] = red2[0][0] + red2[1][0];
        stats[2 * BHN + bid] = mv;
        stats[3 * BHN + bid] = red2[0][1] + red2[1][1];
    }
}

// ---------------- K3b: MFMA GAT aggregation (q and v fused) ----------------
__global__ __launch_bounds__(256) void k_aggr(const float* __restrict__ adj,
        const float* __restrict__ hall, const float* __restrict__ esq,
        const float* __restrict__ edq, const float* __restrict__ esv,
        const float* __restrict__ edv, const float* __restrict__ stats,
        float* __restrict__ outq, float* __restrict__ outv) {
    int it = blockIdx.x, h = blockIdx.y, b = blockIdx.z;
    int i0 = it * 32;
    int t = threadIdx.x;
    int lane = t & 63, wv = t >> 6;
    int mh = wv & 1, kind = wv >> 1;          // 0=q, 1=v
    int bh = b * H + h;

    __shared__ __align__(16) unsigned short hT[128][40];  // [e][j] bf16; 80B rows

    int i = i0 + mh * 16 + (lane & 15);
    int bi = bh * N + i;
    const float* es_p = kind ? esv : esq;
    const float* ed_p = kind ? edv : edq;
    float es_i = es_p[bi];
    float m_i  = stats[2 * kind * BHN + bi];
    float is_i = 1.f / stats[(2 * kind + 1) * BHN + bi];
    const float* adjrow = adj + (size_t)(b * N + i) * N;
    const float* edrow  = ed_p + (size_t)bh * N;
    int klo = lane >> 4;

    int jp = t & 15;
    int eg = t >> 4;
    int ebase = eg * 8;
    int col0 = (ebase < 64) ? (h * 64 + ebase) : (256 + h * 64 + (ebase - 64));

    f32x4 acc[4] = {};
    int erow = kind * 64 + (lane & 15);

    for (int jt = 0; jt < 32; jt++) {
        int j0 = jt * 32;
        float4 a0 = *reinterpret_cast<const float4*>(adjrow + j0 + klo * 8);
        float4 a1 = *reinterpret_cast<const float4*>(adjrow + j0 + klo * 8 + 4);
        float4 e0 = *reinterpret_cast<const float4*>(edrow + j0 + klo * 8);
        float4 e1 = *reinterpret_cast<const float4*>(edrow + j0 + klo * 8 + 4);
        const float* r0 = hall + (size_t)(b * N + j0 + 2 * jp) * COLS + col0;
        float4 f0a = *reinterpret_cast<const float4*>(r0);
        float4 f0b = *reinterpret_cast<const float4*>(r0 + 4);
        float4 f1a = *reinterpret_cast<const float4*>(r0 + COLS);
        float4 f1b = *reinterpret_cast<const float4*>(r0 + COLS + 4);
        __syncthreads();
        {
            float lof[8] = {f0a.x, f0a.y, f0a.z, f0a.w, f0b.x, f0b.y, f0b.z, f0b.w};
            float hif[8] = {f1a.x, f1a.y, f1a.z, f1a.w, f1b.x, f1b.y, f1b.z, f1b.w};
            for (int uu = 0; uu < 8; uu++) {
                int u = (uu + eg) & 7;
                unsigned int wword = (unsigned int)f2bf(lof[u]) |
                                     ((unsigned int)f2bf(hif[u]) << 16);
                reinterpret_cast<unsigned int*>(&hT[ebase + u][0])[jp] = wword;
            }
        }
        float av[8] = {a0.x, a0.y, a0.z, a0.w, a1.x, a1.y, a1.z, a1.w};
        float ev[8] = {e0.x, e0.y, e0.z, e0.w, e1.x, e1.y, e1.z, e1.w};
        short8 afrag;
        for (int u = 0; u < 8; u++) {
            float q = es_i + ev[u];
            q = fmaxf(q, 0.2f * q);
            float wgt = (av[u] > 0.f) ? __expf(q - m_i) * is_i : 0.f;
            afrag[u] = (short)f2bf(wgt);
        }
        __syncthreads();
        for (int nt = 0; nt < 4; nt++) {
            short8 bfrag = *reinterpret_cast<const short8*>(&hT[erow + nt * 16][klo * 8]);
            acc[nt] = __builtin_amdgcn_mfma_f32_16x16x32_bf16(afrag, bfrag, acc[nt], 0, 0, 0);
        }
    }
    float* outp = kind ? outv : outq;
    for (int nt = 0; nt < 4; nt++) {
        for (int r = 0; r < 4; r++) {
            int irow = i0 + mh * 16 + (lane >> 4) * 4 + r;
            int e = nt * 16 + (lane & 15);
            outp[(size_t)(b * N + irow) * 256 + h * 64 + e] = acc[nt][r];
        }
    }
}

// ---------------- K4: expmap0 for query (per-head) and value (concat) ----------------
__global__ void k_expmap(const float* __restrict__ outq, const float* __restrict__ outv,
                         float* __restrict__ query, float* __restrict__ sq,
                         float* __restrict__ val) {
    int p = blockIdx.x, t = threadIdx.x;
    int h = t >> 6, e = t & 63;
    float v = outq[(size_t)p * HD + t];
    float ss = v * v;
    for (int m = 32; m; m >>= 1) ss += __shfl_xor(ss, m);
    float n = fmaxf(sqrtf(ss), EPSF);
    float tn = tanhf(n);
    query[(size_t)p * HD + t] = v * (tn / n);
    if (e == 0) sq[h * BN + p] = tn * tn;

    float vv = outv[(size_t)p * HDV + t];
    float s2 = vv * vv;
    for (int m = 32; m; m >>= 1) s2 += __shfl_xor(s2, m);
    __shared__ float part[4];
    if (e == 0) part[h] = s2;
    __syncthreads();
    float tot = part[0] + part[1] + part[2] + part[3];
    float nv = fmaxf(sqrtf(tot), EPSF);
    float sclv = tanhf(nv) / nv;
    val[(size_t)p * HDV + t] = vv * sclv;
}

// ---------------- K5: MFMA pair-dist (split-bf16 hi/lo) + tanh + head-mean ----------
// reshape(-1,B,N,N) closed form: h=m2%4, m=(n2%4)*256+m2/4, n=(b2*256+n2/4)%1024, b=2a+b2/4
// LDS rows 128B -> XOR-swizzle 16B-chunk by (row&7).
DEV int swzX(int row, int ch) { return row * 64 + ((ch ^ (row & 7)) * 8); }  // ushort index

// truncation hi/lo split: hi=trunc16(v) (exact residual), lo=trunc16(v-hi)
DEV void tsplit(float v, short& hs, short& ls) {
    unsigned vu = __float_as_uint(v);
    float lo = v - __uint_as_float(vu & 0xFFFF0000u);
    hs = (short)(unsigned short)(vu >> 16);
    ls = (short)(unsigned short)(__float_as_uint(lo) >> 16);
}

__global__ __launch_bounds__(256, 3) void k_att(const float* __restrict__ query,
        const float* __restrict__ sq, const float* __restrict__ rr,
        const float* __restrict__ tt, float* __restrict__ m_out) {
    int kc = blockIdx.x >> 1, xh = blockIdx.x & 1;
    int c = blockIdx.y >> 2, h = blockIdx.y & 3;
    int b2 = blockIdx.z;
    int t = threadIdx.x;
    int l = t & 63, w = t >> 6;

    __shared__ __align__(16) unsigned short Xh[64 * 64], Xl[64 * 64];
    __shared__ __align__(16) unsigned short Yh[128 * 64], Yl[128 * 64];
    __shared__ float sqX[64], sqY[128], isX[64], isY[128];

    int nstart = (b2 * 256 + kc * 64) & 1023;
    int mstart = c * 256 + xh * 128;

    int rowX = t >> 2, pX = t & 3;       // X stage: 16 d-values at pX*16
    int rowY = t >> 1, pY = t & 1;       // Y stage: 32 d-values at pY*32

    float tacc[8][4] = {};

    #pragma unroll
    for (int a = 0; a < 4; a++) {
        int b = 2 * a + (b2 >> 2);
        __syncthreads();                  // prev iter's LDS reads complete (WAR)
        {   // stage X: load f32, trunc-split to hi/lo bf16, swizzled writes
            const float4* sx4 = reinterpret_cast<const float4*>(
                query + (size_t)(b * N + nstart + rowX) * HD + h * 64);
            #pragma unroll
            for (int cch = 0; cch < 2; cch++) {
                short8 hx, lx;
                float4 v0 = sx4[pX * 4 + cch * 2];
                float4 v1 = sx4[pX * 4 + cch * 2 + 1];
                float vv[8] = {v0.x, v0.y, v0.z, v0.w, v1.x, v1.y, v1.z, v1.w};
                #pragma unroll
                for (int q = 0; q < 8; q++) { short hs, ls; tsplit(vv[q], hs, ls); hx[q] = hs; lx[q] = ls; }
                int idx = swzX(rowX, pX * 2 + cch);
                *reinterpret_cast<short8*>(&Xh[idx]) = hx;
                *reinterpret_cast<short8*>(&Xl[idx]) = lx;
            }
        }
        {   // stage Y
            const float4* sy4 = reinterpret_cast<const float4*>(
                query + (size_t)(b * N + mstart + rowY) * HD + h * 64);
            #pragma unroll
            for (int cch = 0; cch < 4; cch++) {
                short8 hy, ly;
                float4 v0 = sy4[pY * 8 + cch * 2];
                float4 v1 = sy4[pY * 8 + cch * 2 + 1];
                float vv[8] = {v0.x, v0.y, v0.z, v0.w, v1.x, v1.y, v1.z, v1.w};
                #pragma unroll
                for (int q = 0; q < 8; q++) { short hs, ls; tsplit(vv[q], hs, ls); hy[q] = hs; ly[q] = ls; }
                int idy = swzX(rowY, pY * 4 + cch);
                *reinterpret_cast<short8*>(&Yh[idy]) = hy;
                *reinterpret_cast<short8*>(&Yl[idy]) = ly;
            }
        }
        if (t < 64)  { float s = sq[h * BN + b * N + nstart + t]; sqX[t] = s; isX[t] = __builtin_amdgcn_rcpf(1.f - s); }
        else if (t < 192) { int tt2 = t - 64; float s = sq[h * BN + b * N + mstart + tt2]; sqY[tt2] = s; isY[tt2] = __builtin_amdgcn_rcpf(1.f - s); }
        __syncthreads();                  // staging visible

        // A-fragments: wave w owns X rows w*16..+15
        short8 Ah[2], Al[2];
        #pragma unroll
        for (int kk = 0; kk < 2; kk++) {
            int rx = w * 16 + (l & 15);
            int idx = swzX(rx, kk * 4 + (l >> 4));
            Ah[kk] = *reinterpret_cast<const short8*>(&Xh[idx]);
            Al[kk] = *reinterpret_cast<const short8*>(&Xl[idx]);
        }
        float ra = rr[a], ta = tt[a];
        float c1 = 2.f * ta;                       // ln2*log2e == 1
        float c0 = c1 * ra * 1.44269504f;          // 2*r*t*log2e
        float sxr[4], ixr[4];
        #pragma unroll
        for (int r = 0; r < 4; r++) {
            int rx = w * 16 + (l >> 4) * 4 + r;
            sxr[r] = sqX[rx];
            ixr[r] = 2.f * isX[rx];
        }
        #pragma unroll
        for (int nt = 0; nt < 8; nt++) {
            int ry = nt * 16 + (l & 15);
            f32x4 acc = {};
            #pragma unroll
            for (int kk = 0; kk < 2; kk++) {
                int idy = swzX(ry, kk * 4 + (l >> 4));
                short8 Bh = *reinterpret_cast<const short8*>(&Yh[idy]);
                short8 Bl = *reinterpret_cast<const short8*>(&Yl[idy]);
                acc = __builtin_amdgcn_mfma_f32_16x16x32_bf16(Ah[kk], Bh, acc, 0, 0, 0);
                acc = __builtin_amdgcn_mfma_f32_16x16x32_bf16(Ah[kk], Bl, acc, 0, 0, 0);
                acc = __builtin_amdgcn_mfma_f32_16x16x32_bf16(Al[kk], Bh, acc, 0, 0, 0);
            }
            float sy = sqY[ry];
            float iy = isY[ry];
            #pragma unroll
            for (int r = 0; r < 4; r++) {
                float diff = fmaxf(fmaf(-2.f, acc[r], sxr[r] + sy), 0.f);
                float ixy = fminf(ixr[r] * iy, 2e7f);          // 2/max(den,1e-7)
                float z = fmaxf(fmaf(diff, ixy, 1.f), 1.f + EPSF);
                float s_ = z + __builtin_amdgcn_sqrtf(fmaf(z, z, -1.f));   // e^dist
                float l2 = __builtin_amdgcn_logf(s_);                      // log2
                float ex = __builtin_amdgcn_exp2f(fmaf(-c1, l2, c0));      // e^{2u}
                float rc = __builtin_amdgcn_rcpf(ex + 1.f);
                tacc[nt][r] += fmaf(-2.f, rc, 1.f);            // tanh(u), NaN-safe
            }
        }
    }
    // write-out (scrambled reshape positions)
    #pragma unroll
    for (int nt = 0; nt < 8; nt++) {
        #pragma unroll
        for (int r = 0; r < 4; r++) {
            int n_local = w * 16 + (l >> 4) * 4 + r;
            int n2 = c + 4 * (kc * 64 + n_local);
            int mloc = xh * 128 + nt * 16 + (l & 15);
            int m2 = 4 * mloc + h;
            m_out[((size_t)b2 << 20) + ((size_t)n2 << 10) + m2] = 0.25f * tacc[nt][r];
        }
    }
}

// ---------------- K6: in-place symmetrize on d_out att region ----------------
__global__ void k_sym(float* __restrict__ m) {
    int ti = blockIdx.x, tj = blockIdx.y, b = blockIdx.z;
    if (ti > tj) return;
    __shared__ float A[32][33], Bt[32][33];
    int t = threadIdx.x;
    int r = t >> 3, c4 = (t & 7) * 4;
    size_t baseA = ((size_t)b << 20) + (size_t)(ti * 32) * N + tj * 32;
    size_t baseB = ((size_t)b << 20) + (size_t)(tj * 32) * N + ti * 32;
    float4 ua = *reinterpret_cast<const float4*>(m + baseA + (size_t)r * N + c4);
    float4 ub = *reinterpret_cast<const float4*>(m + baseB + (size_t)r * N + c4);
    A[r][c4 + 0] = ua.x; A[r][c4 + 1] = ua.y; A[r][c4 + 2] = ua.z; A[r][c4 + 3] = ua.w;
    Bt[r][c4 + 0] = ub.x; Bt[r][c4 + 1] = ub.y; Bt[r][c4 + 2] = ub.z; Bt[r][c4 + 3] = ub.w;
    __syncthreads();
    for (int u = 0; u < 4; u++) {
        int cc = c4 + u;
        float oa = 0.5f * (A[r][cc] + Bt[cc][r]);
        float ob = 0.5f * (Bt[r][cc] + A[cc][r]);
        m[baseA + (size_t)r * N + cc] = oa;
        m[baseB + (size_t)r * N + cc] = ob;
    }
}

extern "C" void kernel_launch(void* const* d_in, const int* in_sizes, int n_in,
                              void* d_out, int out_size, void* d_ws, size_t ws_size,
                              hipStream_t stream) {
    const float* x   = (const float*)d_in[0];
    const float* adj = (const float*)d_in[1];
    const float* Wq  = (const float*)d_in[3];
    const float* aqs = (const float*)d_in[4];
    const float* aqd = (const float*)d_in[5];
    const float* Wv  = (const float*)d_in[6];
    const float* avs = (const float*)d_in[7];
    const float* avd = (const float*)d_in[8];
    const float* rr  = (const float*)d_in[9];
    const float* tt  = (const float*)d_in[10];

    float* ws = (float*)d_ws;
    float* s     = ws;                            // 8192
    float* Wc    = s + BN;                        // 131072
    float* hall  = Wc + 256 * COLS;               // 4194304
    float* esq   = hall + (size_t)BN * COLS;      // 32768 x4
    float* edq   = esq + BHN;
    float* esv   = edq + BHN;
    float* edv   = esv + BHN;
    float* stats = edv + BHN;                     // 4*BHN
    float* outq  = stats + 4 * BHN;               // 2097152
    float* outv  = outq + (size_t)BN * HD;        // 2097152
    float* query = outq;                          // in-place over outq (element-local)
    float* sq    = outv + (size_t)BN * HDV;       // 32768
    size_t need = (size_t)(sq + H * BN - ws) * sizeof(float);
    if (ws_size < need) return;                   // ws too small: bail visibly

    float* val  = (float*)d_out;
    float* matt = (float*)d_out + (size_t)BN * HDV;

    k_scale<<<BN / 4, 256, 0, stream>>>(x, s);
    k_wcat<<<(256 * COLS) / 256, 256, 0, stream>>>(Wq, Wv, Wc);
    k_gemm<<<dim3(BN / 64, COLS / 64), 256, 0, stream>>>(x, s, Wc, hall);
    k_esed<<<BN, 256, 0, stream>>>(hall, aqs, aqd, avs, avd, esq, edq, esv, edv);
    k_stats<<<BHN, 128, 0, stream>>>(adj, esq, edq, esv, edv, stats);
    k_aggr<<<dim3(32, H, B), 256, 0, stream>>>(adj, hall, esq, edq, esv, edv, stats, outq, outv);
    k_expmap<<<BN, 256, 0, stream>>>(outq, outv, query, sq, val);
    k_att<<<dim3(8, 16, 8), 256, 0, stream>>>(query, sq, rr, tt, matt);
    k_sym<<<dim3(32, 32, 8), 256, 0, stream>>>(matt);
}

// Round 7
// 276.384 us; speedup vs baseline: 2.2327x; 1.0222x over previous
//
#include <hip/hip_runtime.h>
#include <hip/hip_bf16.h>
#include <math.h>

#define DEV __device__ __forceinline__

constexpr int B = 8, N = 1024, DIN = 256, H = 4, DATT = 64, DV = 64;
constexpr int BN = B * N;             // 8192
constexpr int HD = H * DATT;          // 256
constexpr int HDV = H * DV;           // 256
constexpr int COLS = HD + HDV;        // 512
constexpr int BHN = B * H * N;        // 32768
constexpr float EPSF = 1e-7f;

using short8 = __attribute__((ext_vector_type(8))) short;
using f32x4  = __attribute__((ext_vector_type(4))) float;

DEV unsigned short f2bf(float f) {
    __hip_bfloat16 h = __float2bfloat16(f);
    return *reinterpret_cast<unsigned short*>(&h);
}
DEV float bfu2f(unsigned short u) { return __uint_as_float(((unsigned)u) << 16); }

// ---------------- K1: logmap0 row scale: s = artanh(nc)/nc ----------------
__global__ void k_scale(const float* __restrict__ x, float* __restrict__ s) {
    int p = blockIdx.x * 4 + (threadIdx.x >> 6);
    int l = threadIdx.x & 63;
    const float4* xr = reinterpret_cast<const float4*>(x + (size_t)p * DIN);
    float4 u = xr[l];
    float ss = u.x * u.x + u.y * u.y + u.z * u.z + u.w * u.w;
    for (int m = 32; m; m >>= 1) ss += __shfl_xor(ss, m);
    if (l == 0) {
        float n = sqrtf(ss);
        n = fminf(fmaxf(n, EPSF), 1.0f - 1e-5f);
        float at = 0.5f * __logf((1.f + n) / (1.f - n));
        s[p] = at / n;
    }
}

// ---------------- K0: build Wcat [256][512] f32 (Wq | Wv) ----------------
__global__ void k_wcat(const float* __restrict__ Wq, const float* __restrict__ Wv,
                       float* __restrict__ Wc) {
    int idx = blockIdx.x * 256 + threadIdx.x;   // < 256*512
    int k = idx >> 9, c = idx & 511;
    int cc = c & 255;
    int h = cc >> 6, e = cc & 63;
    const float* src = (c < HD) ? Wq : Wv;
    Wc[idx] = src[(h * DIN + k) * 64 + e];
}

// ---------------- K2: GEMM h_all[8192][512] = (s*x)[8192][256] @ Wc ----------------
__global__ __launch_bounds__(256) void k_gemm(const float* __restrict__ x,
                                              const float* __restrict__ s,
                                              const float* __restrict__ Wc,
                                              float* __restrict__ hall) {
    __shared__ float As[16][68];
    __shared__ float Bs[16][68];
    int bm = blockIdx.x, bn = blockIdx.y;
    int tid = threadIdx.x;
    int ty = tid >> 4, tx = tid & 15;
    float acc[4][4] = {};
    int rowbase = bm * 64, colbase = bn * 64;
    int am = tid >> 2;
    int ak = (tid & 3) * 4;
    float sc = s[rowbase + am];
    for (int kt = 0; kt < DIN; kt += 16) {
        float4 u = *reinterpret_cast<const float4*>(x + (size_t)(rowbase + am) * DIN + kt + ak);
        As[ak + 0][am] = u.x * sc;
        As[ak + 1][am] = u.y * sc;
        As[ak + 2][am] = u.z * sc;
        As[ak + 3][am] = u.w * sc;
        int bk = tid >> 4, bc = (tid & 15) * 4;
        float4 w4 = *reinterpret_cast<const float4*>(Wc + (size_t)(kt + bk) * COLS + colbase + bc);
        *reinterpret_cast<float4*>(&Bs[bk][bc]) = w4;
        __syncthreads();
        for (int k = 0; k < 16; k++) {
            float4 a4 = *reinterpret_cast<const float4*>(&As[k][ty * 4]);
            float4 b4 = *reinterpret_cast<const float4*>(&Bs[k][tx * 4]);
            float av[4] = {a4.x, a4.y, a4.z, a4.w};
            float bv[4] = {b4.x, b4.y, b4.z, b4.w};
            for (int i = 0; i < 4; i++)
                for (int j = 0; j < 4; j++) acc[i][j] = fmaf(av[i], bv[j], acc[i][j]);
        }
        __syncthreads();
    }
    for (int i = 0; i < 4; i++) {
        float4 o = make_float4(acc[i][0], acc[i][1], acc[i][2], acc[i][3]);
        *reinterpret_cast<float4*>(hall + (size_t)(rowbase + ty * 4 + i) * COLS + colbase + tx * 4) = o;
    }
}

// ---------------- K2b: es/ed dot products, layout [B][H][N] ----------------
__global__ void k_esed(const float* __restrict__ hall, const float* __restrict__ aqs,
                       const float* __restrict__ aqd, const float* __restrict__ avs,
                       const float* __restrict__ avd, float* __restrict__ esq,
                       float* __restrict__ edq, float* __restrict__ esv,
                       float* __restrict__ edv) {
    int p = blockIdx.x;
    int h = threadIdx.x >> 6, e = threadIdx.x & 63;
    float hq = hall[(size_t)p * COLS + h * 64 + e];
    float hv = hall[(size_t)p * COLS + 256 + h * 64 + e];
    float v1 = hq * aqs[h * 64 + e];
    float v2 = hq * aqd[h * 64 + e];
    float v3 = hv * avs[h * 64 + e];
    float v4 = hv * avd[h * 64 + e];
    for (int m = 32; m; m >>= 1) {
        v1 += __shfl_xor(v1, m); v2 += __shfl_xor(v2, m);
        v3 += __shfl_xor(v3, m); v4 += __shfl_xor(v4, m);
    }
    if (e == 0) {
        int b = p >> 10, n = p & 1023;
        int o = (b * H + h) * N + n;
        esq[o] = v1; edq[o] = v2; esv[o] = v3; edv[o] = v4;
    }
}

// ---------------- K3a: per-row softmax stats (max,sum) for q and v ----------------
__global__ void k_stats(const float* __restrict__ adj, const float* __restrict__ esq,
                        const float* __restrict__ edq, const float* __restrict__ esv,
                        const float* __restrict__ edv, float* __restrict__ stats) {
    int bid = blockIdx.x;                 // (b*H + h)*N + i
    int i = bid & 1023;
    int bh = bid >> 10;
    int b = bh >> 2;
    int t = threadIdx.x;                  // 128 threads, 8 j each
    float esqi = esq[bid], esvi = esv[bid];
    const float* arow = adj + (size_t)(b * N + i) * N + t * 8;
    const float* edqr = edq + (size_t)bh * N + t * 8;
    const float* edvr = edv + (size_t)bh * N + t * 8;
    float4 a0 = *reinterpret_cast<const float4*>(arow);
    float4 a1 = *reinterpret_cast<const float4*>(arow + 4);
    float am[8] = {a0.x, a0.y, a0.z, a0.w, a1.x, a1.y, a1.z, a1.w};
    float4 q0 = *reinterpret_cast<const float4*>(edqr);
    float4 q1 = *reinterpret_cast<const float4*>(edqr + 4);
    float4 w0 = *reinterpret_cast<const float4*>(edvr);
    float4 w1 = *reinterpret_cast<const float4*>(edvr + 4);
    float edqv[8] = {q0.x, q0.y, q0.z, q0.w, q1.x, q1.y, q1.z, q1.w};
    float edvv[8] = {w0.x, w0.y, w0.z, w0.w, w1.x, w1.y, w1.z, w1.w};
    float eq[8], ev[8];
    float mq = -1e30f, mv = -1e30f;
    for (int j = 0; j < 8; j++) {
        bool msk = am[j] > 0.f;
        float q = esqi + edqv[j]; q = fmaxf(q, 0.2f * q);
        float v = esvi + edvv[j]; v = fmaxf(v, 0.2f * v);
        eq[j] = msk ? q : -1e30f;
        ev[j] = msk ? v : -1e30f;
        mq = fmaxf(mq, eq[j]); mv = fmaxf(mv, ev[j]);
    }
    __shared__ float red[2][2];
    __shared__ float red2[2][2];
    for (int m = 32; m; m >>= 1) { mq = fmaxf(mq, __shfl_xor(mq, m)); mv = fmaxf(mv, __shfl_xor(mv, m)); }
    int w = t >> 6;
    if ((t & 63) == 0) { red[w][0] = mq; red[w][1] = mv; }
    __syncthreads();
    mq = fmaxf(red[0][0], red[1][0]);
    mv = fmaxf(red[0][1], red[1][1]);
    float sq_ = 0.f, sv_ = 0.f;
    for (int j = 0; j < 8; j++) { sq_ += __expf(eq[j] - mq); sv_ += __expf(ev[j] - mv); }
    for (int m = 32; m; m >>= 1) { sq_ += __shfl_xor(sq_, m); sv_ += __shfl_xor(sv_, m); }
    if ((t & 63) == 0) { red2[w][0] = sq_; red2[w][1] = sv_; }
    __syncthreads();
    if (t == 0) {
        stats[bid] = mq;
        stats[BHN + bid] = red2[0][0] + red2[1][0];
        stats[2 * BHN + bid] = mv;
        stats[3 * BHN + bid] = red2[0][1] + red2[1][1];
    }
}

// ---------------- K3b: MFMA GAT aggregation, 2-team j-split (512 thr) ----------------
// Teams (waves 0-3 / 4-7) each own half the j-range with a private hT buffer;
// partials combined through LDS at the end. 1024 blocks x 8 waves = full TLP.
__global__ __launch_bounds__(512) void k_aggr(const float* __restrict__ adj,
        const float* __restrict__ hall, const float* __restrict__ esq,
        const float* __restrict__ edq, const float* __restrict__ esv,
        const float* __restrict__ edv, const float* __restrict__ stats,
        float* __restrict__ outq, float* __restrict__ outv) {
    int it = blockIdx.x, h = blockIdx.y, b = blockIdx.z;
    int i0 = it * 32;
    int t = threadIdx.x;
    int lane = t & 63, wv = t >> 6;           // 0..7
    int team = wv >> 2;                       // j-half
    int wt = wv & 3;
    int mh = wt & 1, kind = wt >> 1;          // 0=q, 1=v
    int bh = b * H + h;
    int t8 = t & 255;

    __shared__ __align__(16) unsigned short hTb[2][128][40];  // 2 x 10240B
    unsigned short (*hT)[40] = hTb[team];

    int i = i0 + mh * 16 + (lane & 15);
    int bi = bh * N + i;
    const float* es_p = kind ? esv : esq;
    const float* ed_p = kind ? edv : edq;
    float es_i = es_p[bi];
    float m_i  = stats[2 * kind * BHN + bi];
    float is_i = 1.f / stats[(2 * kind + 1) * BHN + bi];
    const float* adjrow = adj + (size_t)(b * N + i) * N;
    const float* edrow  = ed_p + (size_t)bh * N;
    int klo = lane >> 4;

    int jp = t8 & 15;
    int eg = t8 >> 4;
    int ebase = eg * 8;
    int col0 = (ebase < 64) ? (h * 64 + ebase) : (256 + h * 64 + (ebase - 64));

    f32x4 acc[4] = {};
    int erow = kind * 64 + (lane & 15);

    for (int jj = 0; jj < 16; jj++) {
        int j0 = (team * 16 + jj) * 32;
        float4 a0 = *reinterpret_cast<const float4*>(adjrow + j0 + klo * 8);
        float4 a1 = *reinterpret_cast<const float4*>(adjrow + j0 + klo * 8 + 4);
        float4 e0 = *reinterpret_cast<const float4*>(edrow + j0 + klo * 8);
        float4 e1 = *reinterpret_cast<const float4*>(edrow + j0 + klo * 8 + 4);
        const float* r0 = hall + (size_t)(b * N + j0 + 2 * jp) * COLS + col0;
        float4 f0a = *reinterpret_cast<const float4*>(r0);
        float4 f0b = *reinterpret_cast<const float4*>(r0 + 4);
        float4 f1a = *reinterpret_cast<const float4*>(r0 + COLS);
        float4 f1b = *reinterpret_cast<const float4*>(r0 + COLS + 4);
        __syncthreads();                      // prev iter's B-reads complete
        {
            float lof[8] = {f0a.x, f0a.y, f0a.z, f0a.w, f0b.x, f0b.y, f0b.z, f0b.w};
            float hif[8] = {f1a.x, f1a.y, f1a.z, f1a.w, f1b.x, f1b.y, f1b.z, f1b.w};
            for (int uu = 0; uu < 8; uu++) {
                int u = (uu + eg) & 7;
                unsigned int wword = (unsigned int)f2bf(lof[u]) |
                                     ((unsigned int)f2bf(hif[u]) << 16);
                reinterpret_cast<unsigned int*>(&hT[ebase + u][0])[jp] = wword;
            }
        }
        float av[8] = {a0.x, a0.y, a0.z, a0.w, a1.x, a1.y, a1.z, a1.w};
        float ev[8] = {e0.x, e0.y, e0.z, e0.w, e1.x, e1.y, e1.z, e1.w};
        short8 afrag;
        for (int u = 0; u < 8; u++) {
            float q = es_i + ev[u];
            q = fmaxf(q, 0.2f * q);
            float wgt = (av[u] > 0.f) ? __expf(q - m_i) * is_i : 0.f;
            afrag[u] = (short)f2bf(wgt);
        }
        __syncthreads();                      // staging visible
        for (int nt = 0; nt < 4; nt++) {
            short8 bfrag = *reinterpret_cast<const short8*>(&hT[erow + nt * 16][klo * 8]);
            acc[nt] = __builtin_amdgcn_mfma_f32_16x16x32_bf16(afrag, bfrag, acc[nt], 0, 0, 0);
        }
    }

    __syncthreads();                          // all MFMA LDS reads done; hTb reusable
    float* red = reinterpret_cast<float*>(&hTb[0][0][0]);   // 20480B >= 16384B
    if (team == 1) {
        #pragma unroll
        for (int nt = 0; nt < 4; nt++)
            *reinterpret_cast<f32x4*>(&red[t8 * 16 + nt * 4]) = acc[nt];
    }
    __syncthreads();
    if (team == 0) {
        float* outp = kind ? outv : outq;
        #pragma unroll
        for (int nt = 0; nt < 4; nt++) {
            f32x4 p = *reinterpret_cast<const f32x4*>(&red[t8 * 16 + nt * 4]);
            #pragma unroll
            for (int r = 0; r < 4; r++) {
                int irow = i0 + mh * 16 + (lane >> 4) * 4 + r;
                int e = nt * 16 + (lane & 15);
                outp[(size_t)(b * N + irow) * 256 + h * 64 + e] = acc[nt][r] + p[r];
            }
        }
    }
}

// ---------------- K4: expmap0 for query (per-head) and value (concat) ----------------
__global__ void k_expmap(const float* __restrict__ outq, const float* __restrict__ outv,
                         float* __restrict__ query, float* __restrict__ sq,
                         float* __restrict__ val) {
    int p = blockIdx.x, t = threadIdx.x;
    int h = t >> 6, e = t & 63;
    float v = outq[(size_t)p * HD + t];
    float ss = v * v;
    for (int m = 32; m; m >>= 1) ss += __shfl_xor(ss, m);
    float n = fmaxf(sqrtf(ss), EPSF);
    float tn = tanhf(n);
    query[(size_t)p * HD + t] = v * (tn / n);
    if (e == 0) sq[h * BN + p] = tn * tn;

    float vv = outv[(size_t)p * HDV + t];
    float s2 = vv * vv;
    for (int m = 32; m; m >>= 1) s2 += __shfl_xor(s2, m);
    __shared__ float part[4];
    if (e == 0) part[h] = s2;
    __syncthreads();
    float tot = part[0] + part[1] + part[2] + part[3];
    float nv = fmaxf(sqrtf(tot), EPSF);
    float sclv = tanhf(nv) / nv;
    val[(size_t)p * HDV + t] = vv * sclv;
}

// ---------------- K5: MFMA pair-dist (split-bf16 hi/lo) + tanh + head-mean ----------
// reshape(-1,B,N,N) closed form: h=m2%4, m=(n2%4)*256+m2/4, n=(b2*256+n2/4)%1024, b=2a+b2/4
// LDS rows 128B -> XOR-swizzle 16B-chunk by (row&7).
DEV int swzX(int row, int ch) { return row * 64 + ((ch ^ (row & 7)) * 8); }  // ushort index

// truncation hi/lo split: hi=trunc16(v) (exact residual), lo=trunc16(v-hi)
DEV void tsplit(float v, short& hs, short& ls) {
    unsigned vu = __float_as_uint(v);
    float lo = v - __uint_as_float(vu & 0xFFFF0000u);
    hs = (short)(unsigned short)(vu >> 16);
    ls = (short)(unsigned short)(__float_as_uint(lo) >> 16);
}

__global__ __launch_bounds__(256, 3) void k_att(const float* __restrict__ query,
        const float* __restrict__ sq, const float* __restrict__ rr,
        const float* __restrict__ tt, float* __restrict__ m_out) {
    int kc = blockIdx.x >> 1, xh = blockIdx.x & 1;
    int c = blockIdx.y >> 2, h = blockIdx.y & 3;
    int b2 = blockIdx.z;
    int t = threadIdx.x;
    int l = t & 63, w = t >> 6;

    __shared__ __align__(16) unsigned short Xh[64 * 64], Xl[64 * 64];
    __shared__ __align__(16) unsigned short Yh[128 * 64], Yl[128 * 64];
    __shared__ float sqX[64], sqY[128], isX[64], isY[128];

    int nstart = (b2 * 256 + kc * 64) & 1023;
    int mstart = c * 256 + xh * 128;

    int rowX = t >> 2, pX = t & 3;       // X stage: 16 d-values at pX*16
    int rowY = t >> 1, pY = t & 1;       // Y stage: 32 d-values at pY*32

    float tacc[8][4] = {};

    #pragma unroll
    for (int a = 0; a < 4; a++) {
        int b = 2 * a + (b2 >> 2);
        __syncthreads();                  // prev iter's LDS reads complete (WAR)
        {   // stage X: load f32, trunc-split to hi/lo bf16, swizzled writes
            const float4* sx4 = reinterpret_cast<const float4*>(
                query + (size_t)(b * N + nstart + rowX) * HD + h * 64);
            #pragma unroll
            for (int cch = 0; cch < 2; cch++) {
                short8 hx, lx;
                float4 v0 = sx4[pX * 4 + cch * 2];
                float4 v1 = sx4[pX * 4 + cch * 2 + 1];
                float vv[8] = {v0.x, v0.y, v0.z, v0.w, v1.x, v1.y, v1.z, v1.w};
                #pragma unroll
                for (int q = 0; q < 8; q++) { short hs, ls; tsplit(vv[q], hs, ls); hx[q] = hs; lx[q] = ls; }
                int idx = swzX(rowX, pX * 2 + cch);
                *reinterpret_cast<short8*>(&Xh[idx]) = hx;
                *reinterpret_cast<short8*>(&Xl[idx]) = lx;
            }
        }
        {   // stage Y
            const float4* sy4 = reinterpret_cast<const float4*>(
                query + (size_t)(b * N + mstart + rowY) * HD + h * 64);
            #pragma unroll
            for (int cch = 0; cch < 4; cch++) {
                short8 hy, ly;
                float4 v0 = sy4[pY * 8 + cch * 2];
                float4 v1 = sy4[pY * 8 + cch * 2 + 1];
                float vv[8] = {v0.x, v0.y, v0.z, v0.w, v1.x, v1.y, v1.z, v1.w};
                #pragma unroll
                for (int q = 0; q < 8; q++) { short hs, ls; tsplit(vv[q], hs, ls); hy[q] = hs; ly[q] = ls; }
                int idy = swzX(rowY, pY * 4 + cch);
                *reinterpret_cast<short8*>(&Yh[idy]) = hy;
                *reinterpret_cast<short8*>(&Yl[idy]) = ly;
            }
        }
        if (t < 64)  { float s = sq[h * BN + b * N + nstart + t]; sqX[t] = s; isX[t] = __builtin_amdgcn_rcpf(1.f - s); }
        else if (t < 192) { int tt2 = t - 64; float s = sq[h * BN + b * N + mstart + tt2]; sqY[tt2] = s; isY[tt2] = __builtin_amdgcn_rcpf(1.f - s); }
        __syncthreads();                  // staging visible

        // A-fragments: wave w owns X rows w*16..+15
        short8 Ah[2], Al[2];
        #pragma unroll
        for (int kk = 0; kk < 2; kk++) {
            int rx = w * 16 + (l & 15);
            int idx = swzX(rx, kk * 4 + (l >> 4));
            Ah[kk] = *reinterpret_cast<const short8*>(&Xh[idx]);
            Al[kk] = *reinterpret_cast<const short8*>(&Xl[idx]);
        }
        float ra = rr[a], ta = tt[a];
        float c1 = 2.f * ta;                       // ln2*log2e == 1
        float c0 = c1 * ra * 1.44269504f;          // 2*r*t*log2e
        float sxr[4], ixr[4];
        #pragma unroll
        for (int r = 0; r < 4; r++) {
            int rx = w * 16 + (l >> 4) * 4 + r;
            sxr[r] = sqX[rx];
            ixr[r] = 2.f * isX[rx];
        }
        #pragma unroll
        for (int nt = 0; nt < 8; nt++) {
            int ry = nt * 16 + (l & 15);
            f32x4 acc = {};
            #pragma unroll
            for (int kk = 0; kk < 2; kk++) {
                int idy = swzX(ry, kk * 4 + (l >> 4));
                short8 Bh = *reinterpret_cast<const short8*>(&Yh[idy]);
                short8 Bl = *reinterpret_cast<const short8*>(&Yl[idy]);
                acc = __builtin_amdgcn_mfma_f32_16x16x32_bf16(Ah[kk], Bh, acc, 0, 0, 0);
                acc = __builtin_amdgcn_mfma_f32_16x16x32_bf16(Ah[kk], Bl, acc, 0, 0, 0);
                acc = __builtin_amdgcn_mfma_f32_16x16x32_bf16(Al[kk], Bh, acc, 0, 0, 0);
            }
            float sy = sqY[ry];
            float iy = isY[ry];
            #pragma unroll
            for (int r = 0; r < 4; r++) {
                float diff = fmaxf(fmaf(-2.f, acc[r], sxr[r] + sy), 0.f);
                float ixy = fminf(ixr[r] * iy, 2e7f);          // 2/max(den,1e-7)
                float z = fmaxf(fmaf(diff, ixy, 1.f), 1.f + EPSF);
                float s_ = z + __builtin_amdgcn_sqrtf(fmaf(z, z, -1.f));   // e^dist
                float l2 = __builtin_amdgcn_logf(s_);                      // log2
                float ex = __builtin_amdgcn_exp2f(fmaf(-c1, l2, c0));      // e^{2u}
                float rc = __builtin_amdgcn_rcpf(ex + 1.f);
                tacc[nt][r] += fmaf(-2.f, rc, 1.f);            // tanh(u), NaN-safe
            }
        }
    }
    // write-out (scrambled reshape positions)
    #pragma unroll
    for (int nt = 0; nt < 8; nt++) {
        #pragma unroll
        for (int r = 0; r < 4; r++) {
            int n_local = w * 16 + (l >> 4) * 4 + r;
            int n2 = c + 4 * (kc * 64 + n_local);
            int mloc = xh * 128 + nt * 16 + (l & 15);
            int m2 = 4 * mloc + h;
            m_out[((size_t)b2 << 20) + ((size_t)n2 << 10) + m2] = 0.25f * tacc[nt][r];
        }
    }
}

// ---------------- K6: in-place symmetrize on d_out att region ----------------
__global__ void k_sym(float* __restrict__ m) {
    int ti = blockIdx.x, tj = blockIdx.y, b = blockIdx.z;
    if (ti > tj) return;
    __shared__ float A[32][33], Bt[32][33];
    int t = threadIdx.x;
    int r = t >> 3, c4 = (t & 7) * 4;
    size_t baseA = ((size_t)b << 20) + (size_t)(ti * 32) * N + tj * 32;
    size_t baseB = ((size_t)b << 20) + (size_t)(tj * 32) * N + ti * 32;
    float4 ua = *reinterpret_cast<const float4*>(m + baseA + (size_t)r * N + c4);
    float4 ub = *reinterpret_cast<const float4*>(m + baseB + (size_t)r * N + c4);
    A[r][c4 + 0] = ua.x; A[r][c4 + 1] = ua.y; A[r][c4 + 2] = ua.z; A[r][c4 + 3] = ua.w;
    Bt[r][c4 + 0] = ub.x; Bt[r][c4 + 1] = ub.y; Bt[r][c4 + 2] = ub.z; Bt[r][c4 + 3] = ub.w;
    __syncthreads();
    for (int u = 0; u < 4; u++) {
        int cc = c4 + u;
        float oa = 0.5f * (A[r][cc] + Bt[cc][r]);
        float ob = 0.5f * (Bt[r][cc] + A[cc][r]);
        m[baseA + (size_t)r * N + cc] = oa;
        m[baseB + (size_t)r * N + cc] = ob;
    }
}

extern "C" void kernel_launch(void* const* d_in, const int* in_sizes, int n_in,
                              void* d_out, int out_size, void* d_ws, size_t ws_size,
                              hipStream_t stream) {
    const float* x   = (const float*)d_in[0];
    const float* adj = (const float*)d_in[1];
    const float* Wq  = (const float*)d_in[3];
    const float* aqs = (const float*)d_in[4];
    const float* aqd = (const float*)d_in[5];
    const float* Wv  = (const float*)d_in[6];
    const float* avs = (const float*)d_in[7];
    const float* avd = (const float*)d_in[8];
    const float* rr  = (const float*)d_in[9];
    const float* tt  = (const float*)d_in[10];

    float* ws = (float*)d_ws;
    float* s     = ws;                            // 8192
    float* Wc    = s + BN;                        // 131072
    float* hall  = Wc + 256 * COLS;               // 4194304
    float* esq   = hall + (size_t)BN * COLS;      // 32768 x4
    float* edq   = esq + BHN;
    float* esv   = edq + BHN;
    float* edv   = esv + BHN;
    float* stats = edv + BHN;                     // 4*BHN
    float* outq  = stats + 4 * BHN;               // 2097152
    float* outv  = outq + (size_t)BN * HD;        // 2097152
    float* query = outq;                          // in-place over outq (element-local)
    float* sq    = outv + (size_t)BN * HDV;       // 32768
    size_t need = (size_t)(sq + H * BN - ws) * sizeof(float);
    if (ws_size < need) return;                   // ws too small: bail visibly

    float* val  = (float*)d_out;
    float* matt = (float*)d_out + (size_t)BN * HDV;

    k_scale<<<BN / 4, 256, 0, stream>>>(x, s);
    k_wcat<<<(256 * COLS) / 256, 256, 0, stream>>>(Wq, Wv, Wc);
    k_gemm<<<dim3(BN / 64, COLS / 64), 256, 0, stream>>>(x, s, Wc, hall);
    k_esed<<<BN, 256, 0, stream>>>(hall, aqs, aqd, avs, avd, esq, edq, esv, edv);
    k_stats<<<BHN, 128, 0, stream>>>(adj, esq, edq, esv, edv, stats);
    k_aggr<<<dim3(32, H, B), 512, 0, stream>>>(adj, hall, esq, edq, esv, edv, stats, outq, outv);
    k_expmap<<<BN, 256, 0, stream>>>(outq, outv, query, sq, val);
    k_att<<<dim3(8, 16, 8), 256, 0, stream>>>(query, sq, rr, tt, matt);
    k_sym<<<dim3(32, 32, 8), 256, 0, stream>>>(matt);
}